// Round 5
// baseline (1059.564 us; speedup 1.0000x reference)
//
#include <hip/hip_runtime.h>

// EquivariantConvLayer — Round 5.
// msg0e ss-path factorized: G[n] = s[n] @ wss per node (10.5 GF GEMM, f16,
// fragment-linear layout), consumed per src-sorted 16-padded edge tile as
// msg0_ss = es @ G[src] (8 MFMA/tile). Two edge orders: padded-src for msg0e,
// dst for msg1o/gathers, linked by map[]. G split over S passes to fit ws.

#define NN 20000
#define EE 640000
#define D0 64
#define D1 32
#define HH 64
#define EPMAX 940032          // E + 15*N rounded to 256
#define NTILES 58752          // EPMAX/16

typedef _Float16 half8 __attribute__((ext_vector_type(8)));
typedef _Float16 half4 __attribute__((ext_vector_type(4)));
typedef float f32x4 __attribute__((ext_vector_type(4)));

__device__ __forceinline__ float silu_f(float x) { return x / (1.0f + __expf(-x)); }
__device__ __forceinline__ _Float16 u2h(unsigned short u) {
    union { unsigned short u; _Float16 h; } c; c.u = u; return c.h;
}
__device__ __forceinline__ unsigned short h2u(_Float16 h) {
    union { unsigned short u; _Float16 h; } c; c.h = h; return c.u;
}
__device__ __forceinline__ half8 pack8(float4 a, float4 b) {
    half8 h;
    h[0]=(_Float16)a.x; h[1]=(_Float16)a.y; h[2]=(_Float16)a.z; h[3]=(_Float16)a.w;
    h[4]=(_Float16)b.x; h[5]=(_Float16)b.y; h[6]=(_Float16)b.z; h[7]=(_Float16)b.w;
    return h;
}

// ---- workspace layout (bytes) ----
// common / round-4 tier
#define OFF_HIST  0ull
#define OFF_RS    81920ull
#define OFF_CUR   163840ull
#define OFF_FLAG  245760ull
#define OFF_EPT   245764ull
#define OFF_SRCA  262144ull
#define OFF_DSTA  2822144ull
#define OFF_PE    5382144ull
#define OFF_WSS   7942144ull      // r4 layout (middle tier)
#define OFF_WVS2  8466432ull
#define OFF_WVV   8597504ull
#define OFF_WSV   8601600ull
#define OFF_WX    8605696ull
#define OFF_WMLP  8607744ull
#define OFF_MSG   8632320ull      // 122880000 (msg1 E*192; msg0 EPMAX*128 fits)
#define WS_R4_NEED 131512320ull
// big tier extras
#define OFF_WSSG  131512320ull    // 524288
#define OFF_OUTD  132036608ull    // 81920
#define OFF_PSP   132118528ull    // 81920
#define OFF_CURS  132200448ull    // 81920
#define OFF_SRCT  132282368ull    // 245760 (NTILES*4 used)
#define OFF_POSOF 132528128ull    // 2560000
#define OFF_MAP   135088128ull    // 2560000
#define OFF_DSTP  137648128ull    // 3760128
#define OFF_PEP   141408256ull    // 3760128
#define OFF_G     145168384ull    // npp*8192 per pass
#define NEED_S(npp) (OFF_G + (unsigned long long)(npp) * 8192ull)

// ---------------------------------------------------------------------------
__global__ void detect_idx_kernel(const int* __restrict__ eidx, int* __restrict__ flag) {
    int odd_nz = 0, even_nz = 0;
    for (int k = 0; k < 64; ++k) {
        if (eidx[2 * k + 1] != 0) odd_nz = 1;
        if (eidx[2 * k] != 0) even_nz = 1;
    }
    *flag = (!odd_nz && even_nz) ? 1 : 0;  // 1 => int64
}

__device__ __forceinline__ void load_sd(const int* eidx, const int* flag, int e,
                                        int& s_, int& d_) {
    if (*flag) { s_ = (int)((const long long*)eidx)[e]; d_ = (int)((const long long*)eidx)[EE + e]; }
    else       { s_ = eidx[e];                          d_ = eidx[EE + e]; }
}

__global__ __launch_bounds__(256) void hist_kernel(
    const int* __restrict__ eidx, const int* __restrict__ flag, int* __restrict__ hist)
{
    const int e = blockIdx.x * 256 + threadIdx.x;
    int s_, d_; load_sd(eidx, flag, e, s_, d_);
    atomicAdd(hist + d_, 1);
}

__global__ __launch_bounds__(256) void hist2_kernel(
    const int* __restrict__ eidx, const int* __restrict__ flag,
    int* __restrict__ hist, int* __restrict__ outd)
{
    const int e = blockIdx.x * 256 + threadIdx.x;
    int s_, d_; load_sd(eidx, flag, e, s_, d_);
    atomicAdd(hist + d_, 1);
    atomicAdd(outd + s_, 1);
}

__global__ __launch_bounds__(1024) void scan_kernel(
    const int* __restrict__ hist, int* __restrict__ rs, int* __restrict__ cur)
{
    __shared__ int part[1024];
    const int t = threadIdx.x;
    const int base = t * 20;
    int loc[20];
    int tot = 0;
#pragma unroll
    for (int k = 0; k < 20; ++k) {
        int n = base + k;
        int h = (n < NN) ? hist[n] : 0;
        loc[k] = tot; tot += h;
    }
    part[t] = tot;
    __syncthreads();
    for (int off = 1; off < 1024; off <<= 1) {
        int v = (t >= off) ? part[t - off] : 0;
        __syncthreads();
        part[t] += v;
        __syncthreads();
    }
    int excl = part[t] - tot;
#pragma unroll
    for (int k = 0; k < 20; ++k) {
        int n = base + k;
        if (n < NN) { rs[n] = excl + loc[k]; cur[n] = excl + loc[k]; }
    }
    if (t == 1023) rs[NN] = part[1023];
}

// padded (to 16) prefix over src out-degrees; fills per-tile src table.
__global__ __launch_bounds__(1024) void scanP_kernel(
    const int* __restrict__ outd, int* __restrict__ psP, int* __restrict__ curS,
    int* __restrict__ srcT, int* __restrict__ epT)
{
    __shared__ int part[1024];
    const int t = threadIdx.x;
    const int base = t * 20;
    int loc[20];
    int tot = 0;
#pragma unroll
    for (int k = 0; k < 20; ++k) {
        int n = base + k;
        int p = (n < NN) ? ((outd[n] + 15) & ~15) : 0;
        loc[k] = tot; tot += p;
    }
    part[t] = tot;
    __syncthreads();
    for (int off = 1; off < 1024; off <<= 1) {
        int v = (t >= off) ? part[t - off] : 0;
        __syncthreads();
        part[t] += v;
        __syncthreads();
    }
    int excl = part[t] - tot;
#pragma unroll
    for (int k = 0; k < 20; ++k) {
        int n = base + k;
        if (n < NN) {
            int start = excl + loc[k];
            psP[n] = start; curS[n] = start;
            int p = (outd[n] + 15) & ~15;
            for (int tt = start >> 4; tt < (start + p) >> 4; ++tt) srcT[tt] = n;
        }
    }
    if (t == 1023) *epT = part[1023] >> 4;
}

__global__ __launch_bounds__(256) void fillpad_kernel(
    const int* __restrict__ epT, int* __restrict__ srcT)
{
    int t = blockIdx.x * 256 + threadIdx.x;
    if (t < NTILES && t >= *epT) srcT[t] = NN;
}

__global__ __launch_bounds__(256) void srcscat_kernel(
    const int* __restrict__ eidx, const int* __restrict__ flag,
    int* __restrict__ curS, int* __restrict__ dstP, int* __restrict__ peP,
    int* __restrict__ posof)
{
    const int e = blockIdx.x * 256 + threadIdx.x;
    int s_, d_; load_sd(eidx, flag, e, s_, d_);
    int pos = atomicAdd(curS + s_, 1);
    dstP[pos] = d_; peP[pos] = e; posof[e] = pos;
}

__global__ __launch_bounds__(256) void dstscat2_kernel(
    const int* __restrict__ eidx, const int* __restrict__ flag,
    int* __restrict__ cur, int* __restrict__ srca, int* __restrict__ dsta,
    int* __restrict__ pe, const int* __restrict__ posof, int* __restrict__ map)
{
    const int e = blockIdx.x * 256 + threadIdx.x;
    int s_, d_; load_sd(eidx, flag, e, s_, d_);
    int j = atomicAdd(cur + d_, 1);
    srca[j] = s_; dsta[j] = d_; pe[j] = e;
    if (map) map[j] = posof[e];
}

__global__ __launch_bounds__(256) void scatter_r4_kernel(
    const int* __restrict__ eidx, const int* __restrict__ flag,
    int* __restrict__ cur, int* __restrict__ srca, int* __restrict__ dsta,
    int* __restrict__ pe)
{
    const int e = blockIdx.x * 256 + threadIdx.x;
    int s_, d_; load_sd(eidx, flag, e, s_, d_);
    int pos = atomicAdd(cur + d_, 1);
    srca[pos] = s_; dsta[pos] = d_; pe[pos] = e;
}

// ---------------------------------------------------------------------------
// Weight permutations into MFMA fragment-linear f16 layouts.
__global__ __launch_bounds__(256) void prep_kernel(
    const float* __restrict__ wss, const float* __restrict__ wvv,
    const float* __restrict__ wsv, const float* __restrict__ wvs,
    const float* __restrict__ wx,
    const float* __restrict__ W1, const float* __restrict__ W2,
    const float* __restrict__ W3, char* __restrict__ ws, int maxid)
{
    int id = blockIdx.x * 256 + threadIdx.x;
    if (id >= maxid) return;
    int l = id & 63;
    int l4 = l >> 4, l16 = l & 15;
    half8 o;
    _Float16* dst;
    if (id < 32768) {                       // wss (r4 path): p(64) x frag(8)
        int p = id >> 9; int frag = (id >> 6) & 7;
        int kf = frag >> 2, nf = frag & 3;
#pragma unroll
        for (int j = 0; j < 8; j++) {
            int h = kf * 32 + l4 * 8 + j, oo = nf * 16 + l16;
            o[j] = (_Float16)wss[((size_t)p * 64 + h) * 64 + oo];
        }
        dst = (_Float16*)(ws + OFF_WSS) + (size_t)id * 8;
    } else if (id < 40960) {                // wvs2: B[h][col=d*32+c]
        int i = id - 32768;
        int f = i >> 6;
        int chunk = f >> 3, kf = (f >> 2) & 1, nfl = f & 3;
#pragma unroll
        for (int j = 0; j < 8; j++) {
            int h = kf * 32 + l4 * 8 + j;
            int col = chunk * 64 + nfl * 16 + l16;
            int d = col >> 5, c = col & 31;
            o[j] = (_Float16)wvs[((size_t)d * 64 + h) * 32 + c];
        }
        dst = (_Float16*)(ws + OFF_WVS2) + (size_t)i * 8;
    } else if (id < 41216) {                // wvv
        int i = id - 40960; int nf = i >> 6;
#pragma unroll
        for (int j = 0; j < 8; j++) {
            int d = l4 * 8 + j, oo = nf * 16 + l16;
            o[j] = (_Float16)wvv[d * 64 + oo];
        }
        dst = (_Float16*)(ws + OFF_WVV) + (size_t)i * 8;
    } else if (id < 41472) {                // wsv
        int i = id - 41216; int frag = i >> 6;
        int kf = frag >> 1, nf = frag & 1;
#pragma unroll
        for (int j = 0; j < 8; j++) {
            int p = kf * 32 + l4 * 8 + j, c = nf * 16 + l16;
            o[j] = (_Float16)wsv[p * 32 + c];
        }
        dst = (_Float16*)(ws + OFF_WSV) + (size_t)i * 8;
    } else if (id < 41600) {                // wcross
        int i = id - 41472; int nf = i >> 6;
#pragma unroll
        for (int j = 0; j < 8; j++) {
            int d = l4 * 8 + j, c = nf * 16 + l16;
            o[j] = (_Float16)wx[d * 32 + c];
        }
        dst = (_Float16*)(ws + OFF_WX) + (size_t)i * 8;
    } else if (id < 43136) {                // W1..W3
        int i = id - 41600; int f = i >> 6;
        int layer = f >> 3, kf = (f >> 2) & 1, nf = f & 3;
        const float* W = layer == 0 ? W1 : (layer == 1 ? W2 : W3);
#pragma unroll
        for (int j = 0; j < 8; j++) {
            int r = kf * 32 + l4 * 8 + j, cc = nf * 16 + l16;
            o[j] = (_Float16)W[r * 64 + cc];
        }
        dst = (_Float16*)(ws + OFF_WMLP) + (size_t)i * 8;
    } else {                                // wssG: B[p][cc], cc = G frag-linear
        int i = id - 43136;                 // 0..32767
        int f = i >> 6;                     // q*8 + kfp*4 + nfp
        int q = f >> 3, kfp = (f >> 2) & 1, nfp = f & 3;
#pragma unroll
        for (int j = 0; j < 8; j++) {
            int p = kfp * 32 + l4 * 8 + j;
            int cc = q * 64 + nfp * 16 + l16;
            // decode cc -> (h,o) per consume frag layout
            int jc = cc & 7, lc = (cc >> 3) & 63, fi = cc >> 9;
            int kfc = fi >> 2, nfc = fi & 3;
            int h = kfc * 32 + (lc >> 4) * 8 + jc;
            int oo = nfc * 16 + (lc & 15);
            o[j] = (_Float16)wss[((size_t)p * 64 + h) * 64 + oo];
        }
        dst = (_Float16*)(ws + OFF_WSSG) + (size_t)i * 8;
    }
    *(half8*)dst = o;
}

// ---------------------------------------------------------------------------
// G[n] = s[n] @ wss, stored fragment-linear (node-major, 4096 f16/node).
__global__ __launch_bounds__(256, 2) void gG_kernel(
    const float* __restrict__ feat0e, const char* __restrict__ wsp,
    int lo, int hi, _Float16* __restrict__ G)
{
    const int tid = threadIdx.x, w = tid >> 6, lane = tid & 63;
    const int l4 = lane >> 4, l16 = lane & 15;
    const int n0 = lo + blockIdx.x * 64 + w * 16;
    if (n0 >= hi) return;

    half8 af[2];
    {
        int n = n0 + l16; if (n >= NN) n = NN - 1;
        const float* sp = feat0e + (size_t)n * 64 + l4 * 8;
        af[0] = pack8(*(const float4*)sp, *(const float4*)(sp + 4));
        af[1] = pack8(*(const float4*)(sp + 32), *(const float4*)(sp + 36));
    }
    const half8* wg = (const half8*)(wsp + OFF_WSSG);
    for (int q = 0; q < 64; ++q) {
        f32x4 acc[4];
#pragma unroll
        for (int nf = 0; nf < 4; nf++) acc[nf] = (f32x4){0.f,0.f,0.f,0.f};
#pragma unroll
        for (int kf = 0; kf < 2; kf++)
#pragma unroll
            for (int nf = 0; nf < 4; nf++)
                acc[nf] = __builtin_amdgcn_mfma_f32_16x16x32_f16(
                    af[kf], wg[(q * 8 + kf * 4 + nf) * 64 + lane], acc[nf], 0, 0, 0);
#pragma unroll
        for (int nf = 0; nf < 4; nf++)
#pragma unroll
            for (int reg = 0; reg < 4; reg++) {
                int n = n0 + l4 * 4 + reg;
                if (n < hi && n < NN)
                    G[(size_t)(n - lo) * 4096 + q * 64 + nf * 16 + l16] =
                        (_Float16)acc[nf][reg];
            }
    }
}

// ---------------------------------------------------------------------------
// Fused MLP (per wave, LDS exchange, no barriers). Produces es A-frags.
__device__ __forceinline__ void mlp_wave(
    const float* __restrict__ edge_attr,
    const float* __restrict__ b1, const float* __restrict__ b2,
    const float* __restrict__ b3,
    const char* __restrict__ wsp,
    const int* __restrict__ pel_w,
    unsigned short* __restrict__ xch,
    int lane, half8 esf[4][2])
{
    const int l4 = lane >> 4, l16 = lane & 15;
    const half8* wm = (const half8*)(wsp + OFF_WMLP);

    float bias[3][4];
#pragma unroll
    for (int nf = 0; nf < 4; nf++) {
        bias[0][nf] = b1[nf * 16 + l16];
        bias[1][nf] = b2[nf * 16 + l16];
        bias[2][nf] = b3[nf * 16 + l16];
    }

    half8 af[4][2];
#pragma unroll
    for (int mf = 0; mf < 4; mf++) {
        int e = pel_w[mf * 16 + l16];
        const float* p = edge_attr + (size_t)e * 64 + l4 * 8;
#pragma unroll
        for (int kf = 0; kf < 2; kf++)
            af[mf][kf] = pack8(*(const float4*)(p + kf * 32),
                               *(const float4*)(p + kf * 32 + 4));
    }

#pragma unroll
    for (int layer = 0; layer < 3; ++layer) {
        f32x4 acc[4][4];
#pragma unroll
        for (int mf = 0; mf < 4; mf++)
#pragma unroll
            for (int nf = 0; nf < 4; nf++) acc[mf][nf] = (f32x4){0.f,0.f,0.f,0.f};
#pragma unroll
        for (int kf = 0; kf < 2; kf++)
#pragma unroll
            for (int mf = 0; mf < 4; mf++)
#pragma unroll
                for (int nf = 0; nf < 4; nf++)
                    acc[mf][nf] = __builtin_amdgcn_mfma_f32_16x16x32_f16(
                        af[mf][kf], wm[(layer * 8 + kf * 4 + nf) * 64 + lane],
                        acc[mf][nf], 0, 0, 0);
#pragma unroll
        for (int mf = 0; mf < 4; mf++)
#pragma unroll
            for (int nf = 0; nf < 4; nf++)
#pragma unroll
                for (int reg = 0; reg < 4; reg++) {
                    int row = mf * 16 + l4 * 4 + reg;
                    int col = nf * 16 + l16;
                    float v = acc[mf][nf][reg] + bias[layer][nf];
                    if (layer < 2) v = silu_f(v);
                    xch[row * 64 + (col ^ ((row & 7) << 3))] = h2u((_Float16)v);
                }
        if (layer < 2) {
#pragma unroll
            for (int mf = 0; mf < 4; mf++)
#pragma unroll
                for (int kf = 0; kf < 2; kf++) {
                    int row = mf * 16 + l16;
                    int cs = kf * 32 + l4 * 8;
                    af[mf][kf] = *(const half8*)&xch[row * 64 + (cs ^ ((row & 7) << 3))];
                }
        }
    }
#pragma unroll
    for (int mf = 0; mf < 4; mf++)
#pragma unroll
        for (int kf = 0; kf < 2; kf++) {
            int row = mf * 16 + l16;
            int cs = kf * 32 + l4 * 8;
            esf[mf][kf] = *(const half8*)&xch[row * 64 + (cs ^ ((row & 7) << 3))];
        }
}

// ---------------------------------------------------------------------------
// Big-tier msg0e: padded src-sorted tiles; ss via es@G[src]; no barriers.
__global__ __launch_bounds__(256, 4) void msg0e_big_kernel(
    const float* __restrict__ feat1o,
    const float* __restrict__ edge_attr,
    const float* __restrict__ pos,
    const float* __restrict__ b1, const float* __restrict__ b2,
    const float* __restrict__ b3,
    const char* __restrict__ wsp,
    const _Float16* __restrict__ G,
    int lo, int hi,
    _Float16* __restrict__ msg0)
{
    __shared__ unsigned short st[4][4096];
    __shared__ float rell[4][64][3];
    __shared__ int pel[4][64];

    const int tid = threadIdx.x, w = tid >> 6, lane = tid & 63;
    const int l4 = lane >> 4, l16 = lane & 15;
    const int i0 = blockIdx.x * 256 + w * 64;
    const int t0 = i0 >> 4;

    const int* srcT = (const int*)(wsp + OFF_SRCT);
    int sm[4]; bool act[4]; bool any = false;
#pragma unroll
    for (int mf = 0; mf < 4; mf++) {
        sm[mf] = srcT[t0 + mf];
        act[mf] = (sm[mf] >= lo && sm[mf] < hi);
        any = any || act[mf];
    }
    if (!any) return;

    {
        int row = i0 + lane;
        int my_s = sm[l4];
        int s_ld = my_s < NN ? my_s : 0;
        int d_ = ((const int*)(wsp + OFF_DSTP))[row];
        pel[w][lane] = ((const int*)(wsp + OFF_PEP))[row];
        rell[w][lane][0] = pos[d_ * 3 + 0] - pos[s_ld * 3 + 0];
        rell[w][lane][1] = pos[d_ * 3 + 1] - pos[s_ld * 3 + 1];
        rell[w][lane][2] = pos[d_ * 3 + 2] - pos[s_ld * 3 + 2];
    }

    half8 esf[4][2];
    mlp_wave(edge_attr, b1, b2, b3, wsp, pel[w], st[w], lane, esf);

    f32x4 acc[4][4];
#pragma unroll
    for (int mf = 0; mf < 4; mf++)
#pragma unroll
        for (int nf = 0; nf < 4; nf++) acc[mf][nf] = (f32x4){0.f, 0.f, 0.f, 0.f};

    // ss consume: B = G[src] frags
    const half8* Gb = (const half8*)G;
#pragma unroll
    for (int mf = 0; mf < 4; mf++) {
        if (!act[mf]) continue;
        const half8* gn = Gb + (size_t)(sm[mf] - lo) * 512;
#pragma unroll
        for (int kf = 0; kf < 2; kf++)
#pragma unroll
            for (int nf = 0; nf < 4; nf++) {
                half8 bf = gn[(kf * 4 + nf) * 64 + lane];
                acc[mf][nf] = __builtin_amdgcn_mfma_f32_16x16x32_f16(
                    esf[mf][kf], bf, acc[mf][nf], 0, 0, 0);
            }
    }

    // dotv chunk
    const half8* wvvp = (const half8*)(wsp + OFF_WVV);
#pragma unroll
    for (int mf = 0; mf < 4; mf++) {
        if (!act[mf]) continue;
        int row = mf * 16 + l16;
        float r0 = rell[w][row][0], r1 = rell[w][row][1], r2 = rell[w][row][2];
        const float* vp = feat1o + (size_t)sm[mf] * 96 + l4 * 24;
        float4 A = *(const float4*)(vp + 0),  B = *(const float4*)(vp + 4);
        float4 C = *(const float4*)(vp + 8),  D = *(const float4*)(vp + 12);
        float4 E = *(const float4*)(vp + 16), F = *(const float4*)(vp + 20);
        half8 dvf;
        dvf[0] = (_Float16)(A.x * r0 + A.y * r1 + A.z * r2);
        dvf[1] = (_Float16)(A.w * r0 + B.x * r1 + B.y * r2);
        dvf[2] = (_Float16)(B.z * r0 + B.w * r1 + C.x * r2);
        dvf[3] = (_Float16)(C.y * r0 + C.z * r1 + C.w * r2);
        dvf[4] = (_Float16)(D.x * r0 + D.y * r1 + D.z * r2);
        dvf[5] = (_Float16)(D.w * r0 + E.x * r1 + E.y * r2);
        dvf[6] = (_Float16)(E.z * r0 + E.w * r1 + F.x * r2);
        dvf[7] = (_Float16)(F.y * r0 + F.z * r1 + F.w * r2);
#pragma unroll
        for (int nf = 0; nf < 4; nf++)
            acc[mf][nf] = __builtin_amdgcn_mfma_f32_16x16x32_f16(
                dvf, wvvp[nf * 64 + lane], acc[mf][nf], 0, 0, 0);
    }

    // store via LDS exchange, gated per tile
#pragma unroll
    for (int mf = 0; mf < 4; mf++) {
        if (!act[mf]) continue;
#pragma unroll
        for (int nf = 0; nf < 4; nf++)
#pragma unroll
            for (int reg = 0; reg < 4; reg++) {
                int row = mf * 16 + l4 * 4 + reg;
                int col = nf * 16 + l16;
                st[w][row * 64 + (col ^ ((row & 7) << 3))] =
                    h2u((_Float16)acc[mf][nf][reg]);
            }
    }
#pragma unroll
    for (int t = 0; t < 8; t++) {
        if (!act[t >> 1]) continue;
        int row = t * 8 + (lane >> 3);
        int c8 = lane & 7;
        half8 v = *(const half8*)&st[w][row * 64 + ((c8 * 8) ^ ((row & 7) << 3))];
        *(half8*)(msg0 + (size_t)(i0 + row) * 64 + c8 * 8) = v;
    }
}

// ---------------------------------------------------------------------------
// r4 msg0e (middle tier): full ss einsum with LDS-staged wss.
__global__ __launch_bounds__(256, 2) void msg0e_r4_kernel(
    const float* __restrict__ feat0e,
    const float* __restrict__ feat1o,
    const float* __restrict__ edge_attr,
    const float* __restrict__ pos,
    const float* __restrict__ b1, const float* __restrict__ b2,
    const float* __restrict__ b3,
    const char* __restrict__ wsp,
    _Float16* __restrict__ msg0)
{
    __shared__ unsigned short st[4][4096];
    __shared__ unsigned short wf[16384];
    __shared__ float rell[4][64][3];
    __shared__ int   srcl[4][64];
    __shared__ int   pel[4][64];

    const int tid = threadIdx.x, w = tid >> 6, lane = tid & 63;
    const int l4 = lane >> 4, l16 = lane & 15;
    const long i0 = (long)blockIdx.x * 256 + w * 64;

    {
        long p = i0 + lane;
        int s_ = ((const int*)(wsp + OFF_SRCA))[p];
        int d_ = ((const int*)(wsp + OFF_DSTA))[p];
        pel[w][lane] = ((const int*)(wsp + OFF_PE))[p];
        srcl[w][lane] = s_;
        rell[w][lane][0] = pos[d_ * 3 + 0] - pos[s_ * 3 + 0];
        rell[w][lane][1] = pos[d_ * 3 + 1] - pos[s_ * 3 + 1];
        rell[w][lane][2] = pos[d_ * 3 + 2] - pos[s_ * 3 + 2];
    }
    __syncthreads();

    half8 esf[4][2];
    mlp_wave(edge_attr, b1, b2, b3, wsp, pel[w], st[w], lane, esf);
    __syncthreads();

#pragma unroll
    for (int r4 = 0; r4 < 4; r4++) {
        int row = r4 * 16 + (lane >> 2);
        int ch = lane & 3;
        const float* sp = feat0e + (size_t)srcl[w][row] * 64 + ch * 16;
        half8 h0 = pack8(*(const float4*)(sp + 0), *(const float4*)(sp + 4));
        half8 h1 = pack8(*(const float4*)(sp + 8), *(const float4*)(sp + 12));
        int r7 = row & 7;
        *(half8*)&st[w][row * 64 + (((ch * 2) ^ r7) * 8)]     = h0;
        *(half8*)&st[w][row * 64 + (((ch * 2 + 1) ^ r7) * 8)] = h1;
    }
    __syncthreads();

    f32x4 acc[4][4];
#pragma unroll
    for (int mf = 0; mf < 4; mf++)
#pragma unroll
        for (int nf = 0; nf < 4; nf++) acc[mf][nf] = (f32x4){0.f, 0.f, 0.f, 0.f};

    const half8* wss_g = (const half8*)(wsp + OFF_WSS);
    half8* wfh = (half8*)wf;
    for (int pc = 0; pc < 16; ++pc) {
        __syncthreads();
#pragma unroll
        for (int q = 0; q < 8; q++)
            wfh[q * 256 + tid] = wss_g[pc * 2048 + q * 256 + tid];
        __syncthreads();
#pragma unroll
        for (int pl = 0; pl < 4; ++pl) {
            const int p = pc * 4 + pl;
            _Float16 sv[4];
#pragma unroll
            for (int mf = 0; mf < 4; mf++) {
                int row = mf * 16 + l16;
                sv[mf] = u2h(st[w][row * 64 + (((p >> 3) ^ (row & 7)) * 8) + (p & 7)]);
            }
#pragma unroll
            for (int kf = 0; kf < 2; kf++) {
                half8 bf[4];
#pragma unroll
                for (int nf = 0; nf < 4; nf++)
                    bf[nf] = wfh[(pl * 8 + kf * 4 + nf) * 64 + lane];
#pragma unroll
                for (int mf = 0; mf < 4; mf++) {
                    half8 a = esf[mf][kf] * sv[mf];
#pragma unroll
                    for (int nf = 0; nf < 4; nf++)
                        acc[mf][nf] = __builtin_amdgcn_mfma_f32_16x16x32_f16(a, bf[nf], acc[mf][nf], 0, 0, 0);
                }
            }
        }
    }

    half8 dvf[4];
#pragma unroll
    for (int mf = 0; mf < 4; mf++) {
        int row = mf * 16 + l16;
        int se = srcl[w][row];
        float r0 = rell[w][row][0], r1 = rell[w][row][1], r2 = rell[w][row][2];
        const float* vp = feat1o + (size_t)se * 96 + l4 * 24;
        float4 A = *(const float4*)(vp + 0),  B = *(const float4*)(vp + 4);
        float4 C = *(const float4*)(vp + 8),  D = *(const float4*)(vp + 12);
        float4 E = *(const float4*)(vp + 16), F = *(const float4*)(vp + 20);
        dvf[mf][0] = (_Float16)(A.x * r0 + A.y * r1 + A.z * r2);
        dvf[mf][1] = (_Float16)(A.w * r0 + B.x * r1 + B.y * r2);
        dvf[mf][2] = (_Float16)(B.z * r0 + B.w * r1 + C.x * r2);
        dvf[mf][3] = (_Float16)(C.y * r0 + C.z * r1 + C.w * r2);
        dvf[mf][4] = (_Float16)(D.x * r0 + D.y * r1 + D.z * r2);
        dvf[mf][5] = (_Float16)(D.w * r0 + E.x * r1 + E.y * r2);
        dvf[mf][6] = (_Float16)(E.z * r0 + E.w * r1 + F.x * r2);
        dvf[mf][7] = (_Float16)(F.y * r0 + F.z * r1 + F.w * r2);
    }
    const half8* wvvp = (const half8*)(wsp + OFF_WVV);
#pragma unroll
    for (int nf = 0; nf < 4; nf++) {
        half8 bvv = wvvp[nf * 64 + lane];
#pragma unroll
        for (int mf = 0; mf < 4; mf++)
            acc[mf][nf] = __builtin_amdgcn_mfma_f32_16x16x32_f16(dvf[mf], bvv, acc[mf][nf], 0, 0, 0);
    }

#pragma unroll
    for (int mf = 0; mf < 4; mf++)
#pragma unroll
        for (int nf = 0; nf < 4; nf++)
#pragma unroll
            for (int reg = 0; reg < 4; reg++) {
                int row = mf * 16 + l4 * 4 + reg;
                int col = nf * 16 + l16;
                st[w][row * 64 + (col ^ ((row & 7) << 3))] = h2u((_Float16)acc[mf][nf][reg]);
            }
#pragma unroll
    for (int t = 0; t < 8; t++) {
        int row = t * 8 + (lane >> 3);
        int c8 = lane & 7;
        half8 v = *(const half8*)&st[w][row * 64 + ((c8 * 8) ^ ((row & 7) << 3))];
        *(half8*)(msg0 + (size_t)(i0 + row) * 64 + c8 * 8) = v;
    }
}

// ---------------------------------------------------------------------------
// msg1o (dst-sorted, unchanged from round 4).
__global__ __launch_bounds__(256, 2) void msg1o_kernel(
    const float* __restrict__ feat0e,
    const float* __restrict__ feat1o,
    const float* __restrict__ edge_attr,
    const float* __restrict__ pos,
    const float* __restrict__ b1, const float* __restrict__ b2,
    const float* __restrict__ b3,
    const char* __restrict__ wsp,
    _Float16* __restrict__ msg1)
{
    __shared__ unsigned short vt[4][6144];
    __shared__ float rell[4][64][3];
    __shared__ int srcl[4][64];
    __shared__ int pel[4][64];

    const int tid = threadIdx.x, w = tid >> 6, lane = tid & 63;
    const int l4 = lane >> 4, l16 = lane & 15;
    const long i0 = (long)blockIdx.x * 256 + w * 64;

    {
        long p = i0 + lane;
        int s_ = ((const int*)(wsp + OFF_SRCA))[p];
        int d_ = ((const int*)(wsp + OFF_DSTA))[p];
        pel[w][lane] = ((const int*)(wsp + OFF_PE))[p];
        srcl[w][lane] = s_;
        rell[w][lane][0] = pos[d_ * 3 + 0] - pos[s_ * 3 + 0];
        rell[w][lane][1] = pos[d_ * 3 + 1] - pos[s_ * 3 + 1];
        rell[w][lane][2] = pos[d_ * 3 + 2] - pos[s_ * 3 + 2];
    }
    __syncthreads();

    half8 esf[4][2];
    mlp_wave(edge_attr, b1, b2, b3, wsp, pel[w], vt[w], lane, esf);
    __syncthreads();

    {
        const float* vp = feat1o + (size_t)srcl[w][lane] * 96;
#pragma unroll
        for (int q = 0; q < 24; q++) {
            float4 f = *(const float4*)(vp + q * 4);
            vt[w][(q * 4 + 0) * 64 + lane] = h2u((_Float16)f.x);
            vt[w][(q * 4 + 1) * 64 + lane] = h2u((_Float16)f.y);
            vt[w][(q * 4 + 2) * 64 + lane] = h2u((_Float16)f.z);
            vt[w][(q * 4 + 3) * 64 + lane] = h2u((_Float16)f.w);
        }
    }
    __syncthreads();

    const half8* wvs2p = (const half8*)(wsp + OFF_WVS2);
    const half8* wsvp  = (const half8*)(wsp + OFF_WSV);
    const half8* wxp   = (const half8*)(wsp + OFF_WX);

    f32x4 acc1[4][3][2];
#pragma unroll
    for (int g = 0; g < 4; g++)
#pragma unroll
        for (int x = 0; x < 3; x++)
#pragma unroll
            for (int ch = 0; ch < 2; ch++) acc1[g][x][ch] = (f32x4){0.f,0.f,0.f,0.f};

#pragma unroll 2
    for (int ck = 0; ck < 16; ++ck) {
        half8 bf[2][4];
#pragma unroll
        for (int kf = 0; kf < 2; kf++)
#pragma unroll
            for (int nfl = 0; nfl < 4; nfl++)
                bf[kf][nfl] = wvs2p[(ck * 8 + kf * 4 + nfl) * 64 + lane];
#pragma unroll
        for (int g = 0; g < 4; g++) {
            f32x4 tacc[4];
#pragma unroll
            for (int nfl = 0; nfl < 4; nfl++) tacc[nfl] = (f32x4){0.f,0.f,0.f,0.f};
#pragma unroll
            for (int kf = 0; kf < 2; kf++)
#pragma unroll
                for (int nfl = 0; nfl < 4; nfl++)
                    tacc[nfl] = __builtin_amdgcn_mfma_f32_16x16x32_f16(
                        esf[g][kf], bf[kf][nfl], tacc[nfl], 0, 0, 0);
#pragma unroll
            for (int dl = 0; dl < 2; dl++) {
                int d = ck * 2 + dl;
#pragma unroll
                for (int x = 0; x < 3; x++) {
                    half4 hv = *(const half4*)&vt[w][(d * 3 + x) * 64 + g * 16 + l4 * 4];
                    f32x4 vf = __builtin_convertvector(hv, f32x4);
                    acc1[g][x][0] += vf * tacc[dl * 2 + 0];
                    acc1[g][x][1] += vf * tacc[dl * 2 + 1];
                }
            }
        }
    }

    {
        half8 bsv[2][2];
#pragma unroll
        for (int kf = 0; kf < 2; kf++)
#pragma unroll
            for (int nf = 0; nf < 2; nf++)
                bsv[kf][nf] = wsvp[(size_t)(kf * 2 + nf) * 64 + lane];
#pragma unroll
        for (int g = 0; g < 4; g++) {
            int erow = g * 16 + l16;
            const float* sp = feat0e + (size_t)srcl[w][erow] * 64 + l4 * 8;
            half8 sf[2];
#pragma unroll
            for (int kf = 0; kf < 2; kf++)
                sf[kf] = pack8(*(const float4*)(sp + kf * 32),
                               *(const float4*)(sp + kf * 32 + 4));
#pragma unroll
            for (int x = 0; x < 3; x++) {
                _Float16 rl = (_Float16)rell[w][erow][x];
#pragma unroll
                for (int kf = 0; kf < 2; kf++) {
                    half8 a = sf[kf] * rl;
#pragma unroll
                    for (int nf = 0; nf < 2; nf++)
                        acc1[g][x][nf] = __builtin_amdgcn_mfma_f32_16x16x32_f16(
                            a, bsv[kf][nf], acc1[g][x][nf], 0, 0, 0);
                }
            }
        }
    }

    {
        half8 bx[2];
        bx[0] = wxp[lane];
        bx[1] = wxp[64 + lane];
#pragma unroll
        for (int g = 0; g < 4; g++) {
            f32x4 cx[3][2];
#pragma unroll
            for (int xp = 0; xp < 3; xp++) {
                half8 av;
#pragma unroll
                for (int j = 0; j < 8; j++)
                    av[j] = u2h(vt[w][((l4 * 8 + j) * 3 + xp) * 64 + g * 16 + l16]);
#pragma unroll
                for (int nf = 0; nf < 2; nf++)
                    cx[xp][nf] = __builtin_amdgcn_mfma_f32_16x16x32_f16(
                        av, bx[nf], (f32x4){0.f,0.f,0.f,0.f}, 0, 0, 0);
            }
            f32x4 r[3];
#pragma unroll
            for (int x = 0; x < 3; x++)
#pragma unroll
                for (int reg = 0; reg < 4; reg++)
                    r[x][reg] = rell[w][g * 16 + l4 * 4 + reg][x];
#pragma unroll
            for (int x = 0; x < 3; x++) {
                const int x1 = (x + 1) % 3, x2 = (x + 2) % 3;
#pragma unroll
                for (int ch = 0; ch < 2; ch++)
                    acc1[g][x][ch] += r[x2] * cx[x1][ch] - r[x1] * cx[x2][ch];
            }
        }
    }

    __syncthreads();
#pragma unroll
    for (int g = 0; g < 4; g++)
#pragma unroll
        for (int reg = 0; reg < 4; reg++) {
            int row = g * 16 + l4 * 4 + reg;
            int sw = (row & 3) << 3;
#pragma unroll
            for (int x = 0; x < 3; x++)
#pragma unroll
                for (int ch = 0; ch < 2; ch++) {
                    int c32 = ch * 16 + l16;
                    vt[w][row * 96 + x * 32 + (c32 ^ sw)] = h2u((_Float16)acc1[g][x][ch][reg]);
                }
        }
#pragma unroll
    for (int tt = 0; tt < 12; tt++) {
        int x = tt >> 2, rem = (tt & 3) * 8;
        int col = x * 32 + (rem ^ ((lane & 3) << 3));
        half8 v = *(const half8*)&vt[w][lane * 96 + col];
        *(half8*)(msg1 + (size_t)(i0 + lane) * 96 + tt * 8) = v;
    }
}

// ---------------------------------------------------------------------------
// gather0 (direct rows, middle tier).
__global__ __launch_bounds__(256) void gather0_r4_kernel(
    const float* __restrict__ feat0e,
    const float* __restrict__ Wg, const float* __restrict__ bg,
    const char* __restrict__ wsp, const _Float16* __restrict__ msg0,
    float* __restrict__ out)
{
    __shared__ float Wgl[2048];
    __shared__ float ag[4][64];
    const int tid = threadIdx.x, w = tid >> 6, lane = tid & 63;
    for (int t = tid; t < 2048; t += 256) Wgl[t] = Wg[t];

    const int n = blockIdx.x * 4 + w;
    const int* rs = (const int*)(wsp + OFF_RS);
    const int i0 = rs[n], i1 = rs[n + 1];
    const int r8 = lane >> 3, c8 = lane & 7;

    float a[8];
#pragma unroll
    for (int j = 0; j < 8; j++) a[j] = 0.f;
    for (int i = i0 + r8; i < i1; i += 8) {
        half8 m = *(const half8*)(msg0 + (size_t)i * 64 + c8 * 8);
#pragma unroll
        for (int j = 0; j < 8; j++) a[j] += (float)m[j];
    }
#pragma unroll
    for (int s = 8; s < 64; s <<= 1)
#pragma unroll
        for (int j = 0; j < 8; j++) a[j] += __shfl_xor(a[j], s);
    if (r8 == 0)
#pragma unroll
        for (int j = 0; j < 8; j++) ag[w][c8 * 8 + j] = a[j];
    __syncthreads();

    const float inv = 1.0f / fmaxf((float)(i1 - i0), 1.0f);
    float av = ag[w][lane] * inv;
    out[(size_t)n * 160 + lane] = silu_f(av) + feat0e[(size_t)n * 64 + lane];

    if (lane < 32) {
        float gs = bg[lane];
#pragma unroll
        for (int p = 0; p < 64; ++p) gs = fmaf(ag[w][p] * inv, Wgl[p * 32 + lane], gs);
        out[(size_t)n * 160 + 64 + lane] = silu_f(gs);
    }
}

// gather0 (map-indirect rows, big tier).
__global__ __launch_bounds__(256) void gather0_big_kernel(
    const float* __restrict__ feat0e,
    const float* __restrict__ Wg, const float* __restrict__ bg,
    const char* __restrict__ wsp, const _Float16* __restrict__ msg0,
    float* __restrict__ out)
{
    __shared__ float Wgl[2048];
    __shared__ float ag[4][64];
    const int tid = threadIdx.x, w = tid >> 6, lane = tid & 63;
    for (int t = tid; t < 2048; t += 256) Wgl[t] = Wg[t];

    const int n = blockIdx.x * 4 + w;
    const int* rs = (const int*)(wsp + OFF_RS);
    const int* map = (const int*)(wsp + OFF_MAP);
    const int i0 = rs[n], i1 = rs[n + 1];
    const int r8 = lane >> 3, c8 = lane & 7;

    float a[8];
#pragma unroll
    for (int j = 0; j < 8; j++) a[j] = 0.f;
    for (int i = i0 + r8; i < i1; i += 8) {
        int row = map[i];
        half8 m = *(const half8*)(msg0 + (size_t)row * 64 + c8 * 8);
#pragma unroll
        for (int j = 0; j < 8; j++) a[j] += (float)m[j];
    }
#pragma unroll
    for (int s = 8; s < 64; s <<= 1)
#pragma unroll
        for (int j = 0; j < 8; j++) a[j] += __shfl_xor(a[j], s);
    if (r8 == 0)
#pragma unroll
        for (int j = 0; j < 8; j++) ag[w][c8 * 8 + j] = a[j];
    __syncthreads();

    const float inv = 1.0f / fmaxf((float)(i1 - i0), 1.0f);
    float av = ag[w][lane] * inv;
    out[(size_t)n * 160 + lane] = silu_f(av) + feat0e[(size_t)n * 64 + lane];

    if (lane < 32) {
        float gs = bg[lane];
#pragma unroll
        for (int p = 0; p < 64; ++p) gs = fmaf(ag[w][p] * inv, Wgl[p * 32 + lane], gs);
        out[(size_t)n * 160 + 64 + lane] = silu_f(gs);
    }
}

// ---------------------------------------------------------------------------
__global__ __launch_bounds__(256) void gather1_kernel(
    const float* __restrict__ feat1o,
    const char* __restrict__ wsp, const _Float16* __restrict__ msg1,
    float* __restrict__ out)
{
    __shared__ float ag1[4][96];
    __shared__ float gl[4][32];
    const int tid = threadIdx.x, w = tid >> 6, lane = tid & 63;
    const int n = blockIdx.x * 4 + w;
    const int* rs = (const int*)(wsp + OFF_RS);
    const int i0 = rs[n], i1 = rs[n + 1];

    if (lane < 32) gl[w][lane] = out[(size_t)n * 160 + 64 + lane];

    const int r4 = lane >> 4, c12 = lane & 15;
    float a[8];
#pragma unroll
    for (int j = 0; j < 8; j++) a[j] = 0.f;
    if (c12 < 12)
        for (int i = i0 + r4; i < i1; i += 4) {
            half8 m = *(const half8*)(msg1 + (size_t)i * 96 + c12 * 8);
#pragma unroll
            for (int j = 0; j < 8; j++) a[j] += (float)m[j];
        }
#pragma unroll
    for (int s = 16; s < 64; s <<= 1)
#pragma unroll
        for (int j = 0; j < 8; j++) a[j] += __shfl_xor(a[j], s);
    if (r4 == 0 && c12 < 12)
#pragma unroll
        for (int j = 0; j < 8; j++) ag1[w][c12 * 8 + j] = a[j];
    __syncthreads();

    const float inv = 1.0f / fmaxf((float)(i1 - i0), 1.0f);
#pragma unroll
    for (int t = 0; t < 2; t++) {
        int idx = t * 64 + lane;
        if (idx < 96) {
            int c = idx / 3, x = idx - 3 * c;
            float v = ag1[w][x * 32 + c] * inv * gl[w][c] + feat1o[(size_t)n * 96 + idx];
            out[(size_t)n * 160 + 64 + idx] = v;
        }
    }
}

// ---------------------------------------------------------------------------
extern "C" void kernel_launch(void* const* d_in, const int* in_sizes, int n_in,
                              void* d_out, int out_size, void* d_ws, size_t ws_size,
                              hipStream_t stream) {
    const float* feat0e    = (const float*)d_in[0];
    const float* feat1o    = (const float*)d_in[1];
    const float* edge_attr = (const float*)d_in[2];
    const float* pos       = (const float*)d_in[3];
    const int*   eidx      = (const int*)d_in[4];
    const float* W1 = (const float*)d_in[5];
    const float* b1 = (const float*)d_in[6];
    const float* W2 = (const float*)d_in[7];
    const float* b2 = (const float*)d_in[8];
    const float* W3 = (const float*)d_in[9];
    const float* b3 = (const float*)d_in[10];
    const float* wss    = (const float*)d_in[11];
    const float* wvv    = (const float*)d_in[12];
    const float* wsv    = (const float*)d_in[13];
    const float* wvs    = (const float*)d_in[14];
    const float* wcross = (const float*)d_in[15];
    const float* Wg = (const float*)d_in[16];
    const float* bg = (const float*)d_in[17];

    float* out = (float*)d_out;
    char*  ws  = (char*)d_ws;
    int* hist = (int*)(ws + OFF_HIST);
    int* rs   = (int*)(ws + OFF_RS);
    int* cur  = (int*)(ws + OFF_CUR);
    int* flag = (int*)(ws + OFF_FLAG);
    int* srca = (int*)(ws + OFF_SRCA);
    int* dsta = (int*)(ws + OFF_DSTA);
    int* pe   = (int*)(ws + OFF_PE);
    _Float16* msg = (_Float16*)(ws + OFF_MSG);

    detect_idx_kernel<<<1, 1, 0, stream>>>(eidx, flag);
    hipMemsetAsync(ws + OFF_HIST, 0, NN * sizeof(int), stream);

    // pick number of G passes by available workspace
    int S = 0;
    if (ws_size >= NEED_S(20000)) S = 1;
    else if (ws_size >= NEED_S(10000)) S = 2;
    else if (ws_size >= NEED_S(5000))  S = 4;
    else if (ws_size >= NEED_S(2500))  S = 8;

    if (S > 0) {
        int* outd  = (int*)(ws + OFF_OUTD);
        int* psP   = (int*)(ws + OFF_PSP);
        int* curS  = (int*)(ws + OFF_CURS);
        int* srcT  = (int*)(ws + OFF_SRCT);
        int* epT   = (int*)(ws + OFF_EPT);
        int* posof = (int*)(ws + OFF_POSOF);
        int* map   = (int*)(ws + OFF_MAP);
        int* dstP  = (int*)(ws + OFF_DSTP);
        int* peP   = (int*)(ws + OFF_PEP);
        _Float16* G = (_Float16*)(ws + OFF_G);

        hipMemsetAsync(ws + OFF_OUTD, 0, NN * sizeof(int), stream);
        hipMemsetAsync(ws + OFF_DSTP, 0, 2 * EPMAX * sizeof(int), stream);

        hist2_kernel<<<EE / 256, 256, 0, stream>>>(eidx, flag, hist, outd);
        scan_kernel<<<1, 1024, 0, stream>>>(hist, rs, cur);
        scanP_kernel<<<1, 1024, 0, stream>>>(outd, psP, curS, srcT, epT);
        fillpad_kernel<<<(NTILES + 255) / 256, 256, 0, stream>>>(epT, srcT);
        srcscat_kernel<<<EE / 256, 256, 0, stream>>>(eidx, flag, curS, dstP, peP, posof);
        dstscat2_kernel<<<EE / 256, 256, 0, stream>>>(eidx, flag, cur, srca, dsta, pe,
                                                      posof, map);
        prep_kernel<<<(75904 + 255) / 256, 256, 0, stream>>>(
            wss, wvv, wsv, wvs, wcross, W1, W2, W3, ws, 75904);

        const int npp = (NN + S - 1) / S;
        for (int s = 0; s < S; ++s) {
            int lo = s * npp;
            int hi = lo + npp; if (hi > NN) hi = NN;
            gG_kernel<<<(hi - lo + 63) / 64, 256, 0, stream>>>(
                feat0e, (const char*)ws, lo, hi, G);
            msg0e_big_kernel<<<EPMAX / 256, 256, 0, stream>>>(
                feat1o, edge_attr, pos, b1, b2, b3, (const char*)ws, G, lo, hi, msg);
        }
        gather0_big_kernel<<<NN / 4, 256, 0, stream>>>(
            feat0e, Wg, bg, (const char*)ws, msg, out);
        msg1o_kernel<<<EE / 256, 256, 0, stream>>>(
            feat0e, feat1o, edge_attr, pos, b1, b2, b3, (const char*)ws, msg);
        gather1_kernel<<<NN / 4, 256, 0, stream>>>(
            feat1o, (const char*)ws, msg, out);
    } else {
        // middle tier: round-4 proven path (ws >= 131.5 MB established)
        hist_kernel<<<EE / 256, 256, 0, stream>>>(eidx, flag, hist);
        scan_kernel<<<1, 1024, 0, stream>>>(hist, rs, cur);
        scatter_r4_kernel<<<EE / 256, 256, 0, stream>>>(eidx, flag, cur, srca, dsta, pe);
        prep_kernel<<<(43136 + 255) / 256, 256, 0, stream>>>(
            wss, wvv, wsv, wvs, wcross, W1, W2, W3, ws, 43136);
        msg0e_r4_kernel<<<EE / 256, 256, 0, stream>>>(
            feat0e, feat1o, edge_attr, pos, b1, b2, b3, (const char*)ws, msg);
        gather0_r4_kernel<<<NN / 4, 256, 0, stream>>>(
            feat0e, Wg, bg, (const char*)ws, msg, out);
        msg1o_kernel<<<EE / 256, 256, 0, stream>>>(
            feat0e, feat1o, edge_attr, pos, b1, b2, b3, (const char*)ws, msg);
        gather1_kernel<<<NN / 4, 256, 0, stream>>>(
            feat1o, (const char*)ws, msg, out);
    }
}

// Round 6
// 849.522 us; speedup vs baseline: 1.2472x; 1.2472x over previous
//
#include <hip/hip_runtime.h>

// EquivariantConvLayer — Round 6.
// msg0e: one WAVE per node. G[n] (= s[n]@wss, fragment-linear f16) held in
// 32 VGPRs; wave loops over its ceil(deg/16) edge tiles: MLP-16 -> es@G (8
// MFMA) -> dotv; messages written directly to dst-sorted rows via posDP.
// G traffic = 164 MB (once per node) vs r5's 470 MB. Merged scatter kernel
// builds both orders + posDP in one pass. msg1o/gathers unchanged (verified).

#define NN 20000
#define EE 640000
#define D0 64
#define D1 32
#define HH 64
#define EPMAX 940032          // E + 15*N rounded up

typedef _Float16 half8 __attribute__((ext_vector_type(8)));
typedef _Float16 half4 __attribute__((ext_vector_type(4)));
typedef float f32x4 __attribute__((ext_vector_type(4)));

__device__ __forceinline__ float silu_f(float x) { return x / (1.0f + __expf(-x)); }
__device__ __forceinline__ _Float16 u2h(unsigned short u) {
    union { unsigned short u; _Float16 h; } c; c.u = u; return c.h;
}
__device__ __forceinline__ unsigned short h2u(_Float16 h) {
    union { unsigned short u; _Float16 h; } c; c.h = h; return c.u;
}
__device__ __forceinline__ half8 pack8(float4 a, float4 b) {
    half8 h;
    h[0]=(_Float16)a.x; h[1]=(_Float16)a.y; h[2]=(_Float16)a.z; h[3]=(_Float16)a.w;
    h[4]=(_Float16)b.x; h[5]=(_Float16)b.y; h[6]=(_Float16)b.z; h[7]=(_Float16)b.w;
    return h;
}

// ---- workspace layout (bytes) ----
#define OFF_HIST  0ull
#define OFF_RS    81920ull
#define OFF_CUR   163840ull
#define OFF_FLAG  245760ull
#define OFF_SRCA  262144ull       // E*4 dst-order src
#define OFF_DSTA  2822144ull      // E*4 dst-order dst
#define OFF_PE    5382144ull      // E*4 dst-order edge id
#define OFF_WSS   7942144ull      // 512KB (r4 tier)
#define OFF_WVS2  8466432ull      // 128KB
#define OFF_WVV   8597504ull
#define OFF_WSV   8601600ull
#define OFF_WX    8605696ull
#define OFF_WMLP  8607744ull      // 24KB
#define OFF_MSG   8632320ull      // 122880000
#define WS_R4_NEED 131512320ull
// big tier extras
#define OFF_WSSG  131512320ull    // 512KB
#define OFF_OUTD  132036608ull    // 80KB
#define OFF_PSP   132118528ull    // 80KB
#define OFF_CURS  132200448ull    // 80KB
#define OFF_DSTP  132282368ull    // EPMAX*4
#define OFF_PEP   136042496ull    // EPMAX*4
#define OFF_PDP   139802624ull    // EPMAX*4
#define OFF_G     143562752ull    // npp*8192 per pass
#define NEED_S(npp) (OFF_G + (unsigned long long)(npp) * 8192ull)

// ---------------------------------------------------------------------------
__global__ void detect_idx_kernel(const int* __restrict__ eidx, int* __restrict__ flag) {
    int odd_nz = 0, even_nz = 0;
    for (int k = 0; k < 64; ++k) {
        if (eidx[2 * k + 1] != 0) odd_nz = 1;
        if (eidx[2 * k] != 0) even_nz = 1;
    }
    *flag = (!odd_nz && even_nz) ? 1 : 0;  // 1 => int64
}

__device__ __forceinline__ void load_sd(const int* eidx, const int* flag, int e,
                                        int& s_, int& d_) {
    if (*flag) { s_ = (int)((const long long*)eidx)[e]; d_ = (int)((const long long*)eidx)[EE + e]; }
    else       { s_ = eidx[e];                          d_ = eidx[EE + e]; }
}

__global__ __launch_bounds__(256) void hist_kernel(
    const int* __restrict__ eidx, const int* __restrict__ flag, int* __restrict__ hist)
{
    const int e = blockIdx.x * 256 + threadIdx.x;
    int s_, d_; load_sd(eidx, flag, e, s_, d_);
    atomicAdd(hist + d_, 1);
}

__global__ __launch_bounds__(256) void hist2_kernel(
    const int* __restrict__ eidx, const int* __restrict__ flag,
    int* __restrict__ hist, int* __restrict__ outd)
{
    const int e = blockIdx.x * 256 + threadIdx.x;
    int s_, d_; load_sd(eidx, flag, e, s_, d_);
    atomicAdd(hist + d_, 1);
    atomicAdd(outd + s_, 1);
}

__global__ __launch_bounds__(1024) void scan_kernel(
    const int* __restrict__ hist, int* __restrict__ rs, int* __restrict__ cur)
{
    __shared__ int part[1024];
    const int t = threadIdx.x;
    const int base = t * 20;
    int loc[20];
    int tot = 0;
#pragma unroll
    for (int k = 0; k < 20; ++k) {
        int n = base + k;
        int h = (n < NN) ? hist[n] : 0;
        loc[k] = tot; tot += h;
    }
    part[t] = tot;
    __syncthreads();
    for (int off = 1; off < 1024; off <<= 1) {
        int v = (t >= off) ? part[t - off] : 0;
        __syncthreads();
        part[t] += v;
        __syncthreads();
    }
    int excl = part[t] - tot;
#pragma unroll
    for (int k = 0; k < 20; ++k) {
        int n = base + k;
        if (n < NN) { rs[n] = excl + loc[k]; cur[n] = excl + loc[k]; }
    }
    if (t == 1023) rs[NN] = part[1023];
}

// padded (to 16) prefix over src out-degrees.
__global__ __launch_bounds__(1024) void scanP_kernel(
    const int* __restrict__ outd, int* __restrict__ psP, int* __restrict__ curS)
{
    __shared__ int part[1024];
    const int t = threadIdx.x;
    const int base = t * 20;
    int loc[20];
    int tot = 0;
#pragma unroll
    for (int k = 0; k < 20; ++k) {
        int n = base + k;
        int p = (n < NN) ? ((outd[n] + 15) & ~15) : 0;
        loc[k] = tot; tot += p;
    }
    part[t] = tot;
    __syncthreads();
    for (int off = 1; off < 1024; off <<= 1) {
        int v = (t >= off) ? part[t - off] : 0;
        __syncthreads();
        part[t] += v;
        __syncthreads();
    }
    int excl = part[t] - tot;
#pragma unroll
    for (int k = 0; k < 20; ++k) {
        int n = base + k;
        if (n < NN) { psP[n] = excl + loc[k]; curS[n] = excl + loc[k]; }
    }
}

// single pass: both orders + posDP link (padded-src row -> dst-sorted row).
__global__ __launch_bounds__(256) void scat_both_kernel(
    const int* __restrict__ eidx, const int* __restrict__ flag,
    int* __restrict__ curS, int* __restrict__ cur,
    int* __restrict__ dstP, int* __restrict__ peP, int* __restrict__ pdP,
    int* __restrict__ srca, int* __restrict__ dsta, int* __restrict__ pe)
{
    const int e = blockIdx.x * 256 + threadIdx.x;
    int s_, d_; load_sd(eidx, flag, e, s_, d_);
    int posS = atomicAdd(curS + s_, 1);
    int posD = atomicAdd(cur + d_, 1);
    dstP[posS] = d_; peP[posS] = e; pdP[posS] = posD;
    srca[posD] = s_; dsta[posD] = d_; pe[posD] = e;
}

__global__ __launch_bounds__(256) void scatter_r4_kernel(
    const int* __restrict__ eidx, const int* __restrict__ flag,
    int* __restrict__ cur, int* __restrict__ srca, int* __restrict__ dsta,
    int* __restrict__ pe)
{
    const int e = blockIdx.x * 256 + threadIdx.x;
    int s_, d_; load_sd(eidx, flag, e, s_, d_);
    int pos = atomicAdd(cur + d_, 1);
    srca[pos] = s_; dsta[pos] = d_; pe[pos] = e;
}

// ---------------------------------------------------------------------------
// Weight permutations into MFMA fragment-linear f16 layouts (verified r5).
__global__ __launch_bounds__(256) void prep_kernel(
    const float* __restrict__ wss, const float* __restrict__ wvv,
    const float* __restrict__ wsv, const float* __restrict__ wvs,
    const float* __restrict__ wx,
    const float* __restrict__ W1, const float* __restrict__ W2,
    const float* __restrict__ W3, char* __restrict__ ws, int maxid)
{
    int id = blockIdx.x * 256 + threadIdx.x;
    if (id >= maxid) return;
    int l = id & 63;
    int l4 = l >> 4, l16 = l & 15;
    half8 o;
    _Float16* dst;
    if (id < 32768) {                       // wss (r4 path)
        int p = id >> 9; int frag = (id >> 6) & 7;
        int kf = frag >> 2, nf = frag & 3;
#pragma unroll
        for (int j = 0; j < 8; j++) {
            int h = kf * 32 + l4 * 8 + j, oo = nf * 16 + l16;
            o[j] = (_Float16)wss[((size_t)p * 64 + h) * 64 + oo];
        }
        dst = (_Float16*)(ws + OFF_WSS) + (size_t)id * 8;
    } else if (id < 40960) {                // wvs2: B[h][col=d*32+c]
        int i = id - 32768;
        int f = i >> 6;
        int chunk = f >> 3, kf = (f >> 2) & 1, nfl = f & 3;
#pragma unroll
        for (int j = 0; j < 8; j++) {
            int h = kf * 32 + l4 * 8 + j;
            int col = chunk * 64 + nfl * 16 + l16;
            int d = col >> 5, c = col & 31;
            o[j] = (_Float16)wvs[((size_t)d * 64 + h) * 32 + c];
        }
        dst = (_Float16*)(ws + OFF_WVS2) + (size_t)i * 8;
    } else if (id < 41216) {                // wvv
        int i = id - 40960; int nf = i >> 6;
#pragma unroll
        for (int j = 0; j < 8; j++) {
            int d = l4 * 8 + j, oo = nf * 16 + l16;
            o[j] = (_Float16)wvv[d * 64 + oo];
        }
        dst = (_Float16*)(ws + OFF_WVV) + (size_t)i * 8;
    } else if (id < 41472) {                // wsv
        int i = id - 41216; int frag = i >> 6;
        int kf = frag >> 1, nf = frag & 1;
#pragma unroll
        for (int j = 0; j < 8; j++) {
            int p = kf * 32 + l4 * 8 + j, c = nf * 16 + l16;
            o[j] = (_Float16)wsv[p * 32 + c];
        }
        dst = (_Float16*)(ws + OFF_WSV) + (size_t)i * 8;
    } else if (id < 41600) {                // wcross
        int i = id - 41472; int nf = i >> 6;
#pragma unroll
        for (int j = 0; j < 8; j++) {
            int d = l4 * 8 + j, c = nf * 16 + l16;
            o[j] = (_Float16)wx[d * 32 + c];
        }
        dst = (_Float16*)(ws + OFF_WX) + (size_t)i * 8;
    } else if (id < 43136) {                // W1..W3
        int i = id - 41600; int f = i >> 6;
        int layer = f >> 3, kf = (f >> 2) & 1, nf = f & 3;
        const float* W = layer == 0 ? W1 : (layer == 1 ? W2 : W3);
#pragma unroll
        for (int j = 0; j < 8; j++) {
            int r = kf * 32 + l4 * 8 + j, cc = nf * 16 + l16;
            o[j] = (_Float16)W[r * 64 + cc];
        }
        dst = (_Float16*)(ws + OFF_WMLP) + (size_t)i * 8;
    } else {                                // wssG
        int i = id - 43136;
        int f = i >> 6;
        int q = f >> 3, kfp = (f >> 2) & 1, nfp = f & 3;
#pragma unroll
        for (int j = 0; j < 8; j++) {
            int p = kfp * 32 + l4 * 8 + j;
            int cc = q * 64 + nfp * 16 + l16;
            int jc = cc & 7, lc = (cc >> 3) & 63, fi = cc >> 9;
            int kfc = fi >> 2, nfc = fi & 3;
            int h = kfc * 32 + (lc >> 4) * 8 + jc;
            int oo = nfc * 16 + (lc & 15);
            o[j] = (_Float16)wss[((size_t)p * 64 + h) * 64 + oo];
        }
        dst = (_Float16*)(ws + OFF_WSSG) + (size_t)i * 8;
    }
    *(half8*)dst = o;
}

// ---------------------------------------------------------------------------
// G[n] = s[n] @ wss, fragment-linear (node-major 4096 f16). Verified r5.
__global__ __launch_bounds__(256, 2) void gG_kernel(
    const float* __restrict__ feat0e, const char* __restrict__ wsp,
    int lo, int hi, _Float16* __restrict__ G)
{
    const int tid = threadIdx.x, w = tid >> 6, lane = tid & 63;
    const int l4 = lane >> 4, l16 = lane & 15;
    const int n0 = lo + blockIdx.x * 64 + w * 16;
    if (n0 >= hi) return;

    half8 af[2];
    {
        int n = n0 + l16; if (n >= NN) n = NN - 1;
        const float* sp = feat0e + (size_t)n * 64 + l4 * 8;
        af[0] = pack8(*(const float4*)sp, *(const float4*)(sp + 4));
        af[1] = pack8(*(const float4*)(sp + 32), *(const float4*)(sp + 36));
    }
    const half8* wg = (const half8*)(wsp + OFF_WSSG);
    for (int q = 0; q < 64; ++q) {
        f32x4 acc[4];
#pragma unroll
        for (int nf = 0; nf < 4; nf++) acc[nf] = (f32x4){0.f,0.f,0.f,0.f};
#pragma unroll
        for (int kf = 0; kf < 2; kf++)
#pragma unroll
            for (int nf = 0; nf < 4; nf++)
                acc[nf] = __builtin_amdgcn_mfma_f32_16x16x32_f16(
                    af[kf], wg[(q * 8 + kf * 4 + nf) * 64 + lane], acc[nf], 0, 0, 0);
#pragma unroll
        for (int nf = 0; nf < 4; nf++)
#pragma unroll
            for (int reg = 0; reg < 4; reg++) {
                int n = n0 + l4 * 4 + reg;
                if (n < hi && n < NN)
                    G[(size_t)(n - lo) * 4096 + q * 64 + nf * 16 + l16] =
                        (_Float16)acc[nf][reg];
            }
    }
}

// ---------------------------------------------------------------------------
// Fused MLP, 64-row version (per wave, LDS exchange). Verified r4/r5.
__device__ __forceinline__ void mlp_wave(
    const float* __restrict__ edge_attr,
    const float* __restrict__ b1, const float* __restrict__ b2,
    const float* __restrict__ b3,
    const char* __restrict__ wsp,
    const int* __restrict__ pel_w,
    unsigned short* __restrict__ xch,
    int lane, half8 esf[4][2])
{
    const int l4 = lane >> 4, l16 = lane & 15;
    const half8* wm = (const half8*)(wsp + OFF_WMLP);

    float bias[3][4];
#pragma unroll
    for (int nf = 0; nf < 4; nf++) {
        bias[0][nf] = b1[nf * 16 + l16];
        bias[1][nf] = b2[nf * 16 + l16];
        bias[2][nf] = b3[nf * 16 + l16];
    }

    half8 af[4][2];
#pragma unroll
    for (int mf = 0; mf < 4; mf++) {
        int e = pel_w[mf * 16 + l16];
        const float* p = edge_attr + (size_t)e * 64 + l4 * 8;
#pragma unroll
        for (int kf = 0; kf < 2; kf++)
            af[mf][kf] = pack8(*(const float4*)(p + kf * 32),
                               *(const float4*)(p + kf * 32 + 4));
    }

#pragma unroll
    for (int layer = 0; layer < 3; ++layer) {
        f32x4 acc[4][4];
#pragma unroll
        for (int mf = 0; mf < 4; mf++)
#pragma unroll
            for (int nf = 0; nf < 4; nf++) acc[mf][nf] = (f32x4){0.f,0.f,0.f,0.f};
#pragma unroll
        for (int kf = 0; kf < 2; kf++)
#pragma unroll
            for (int mf = 0; mf < 4; mf++)
#pragma unroll
                for (int nf = 0; nf < 4; nf++)
                    acc[mf][nf] = __builtin_amdgcn_mfma_f32_16x16x32_f16(
                        af[mf][kf], wm[(layer * 8 + kf * 4 + nf) * 64 + lane],
                        acc[mf][nf], 0, 0, 0);
#pragma unroll
        for (int mf = 0; mf < 4; mf++)
#pragma unroll
            for (int nf = 0; nf < 4; nf++)
#pragma unroll
                for (int reg = 0; reg < 4; reg++) {
                    int row = mf * 16 + l4 * 4 + reg;
                    int col = nf * 16 + l16;
                    float v = acc[mf][nf][reg] + bias[layer][nf];
                    if (layer < 2) v = silu_f(v);
                    xch[row * 64 + (col ^ ((row & 7) << 3))] = h2u((_Float16)v);
                }
        if (layer < 2) {
#pragma unroll
            for (int mf = 0; mf < 4; mf++)
#pragma unroll
                for (int kf = 0; kf < 2; kf++) {
                    int row = mf * 16 + l16;
                    int cs = kf * 32 + l4 * 8;
                    af[mf][kf] = *(const half8*)&xch[row * 64 + (cs ^ ((row & 7) << 3))];
                }
        }
    }
#pragma unroll
    for (int mf = 0; mf < 4; mf++)
#pragma unroll
        for (int kf = 0; kf < 2; kf++) {
            int row = mf * 16 + l16;
            int cs = kf * 32 + l4 * 8;
            esf[mf][kf] = *(const half8*)&xch[row * 64 + (cs ^ ((row & 7) << 3))];
        }
}

// ---------------------------------------------------------------------------
// NEW: one wave per node. G in registers; loop over 16-edge tiles.
__global__ __launch_bounds__(256, 3) void msg0e_node_kernel(
    const float* __restrict__ feat1o,
    const float* __restrict__ edge_attr,
    const float* __restrict__ pos,
    const float* __restrict__ b1, const float* __restrict__ b2,
    const float* __restrict__ b3,
    const char* __restrict__ wsp,
    const _Float16* __restrict__ G,
    int lo, int hi,
    _Float16* __restrict__ msg0)
{
    __shared__ half8 wml[1536];                         // 24 KB: W1..W3 frags
    __shared__ __align__(16) unsigned short xch[4][1024]; // 16x64 per wave

    const int tid = threadIdx.x, w = tid >> 6, lane = tid & 63;
    const int l4 = lane >> 4, l16 = lane & 15;

    {
        const half8* wm = (const half8*)(wsp + OFF_WMLP);
        for (int f = tid; f < 1536; f += 256) wml[f] = wm[f];
    }
    __syncthreads();

    const int n = lo + blockIdx.x * 4 + w;
    if (n >= hi) return;
    const int deg = ((const int*)(wsp + OFF_OUTD))[n];
    if (deg == 0) return;
    const int base = ((const int*)(wsp + OFF_PSP))[n];
    const int* dstP = (const int*)(wsp + OFF_DSTP);
    const int* peP  = (const int*)(wsp + OFF_PEP);
    const int* pdP  = (const int*)(wsp + OFF_PDP);

    // wave-constant state
    const float pn0 = pos[n * 3 + 0], pn1 = pos[n * 3 + 1], pn2 = pos[n * 3 + 2];
    half8 Gr[8];
    {
        const half8* gn = (const half8*)G + (size_t)(n - lo) * 512;
#pragma unroll
        for (int f = 0; f < 8; f++) Gr[f] = gn[f * 64 + lane];
    }
    half8 wvvf[4];
    {
        const half8* wvvp = (const half8*)(wsp + OFF_WVV);
#pragma unroll
        for (int nf = 0; nf < 4; nf++) wvvf[nf] = wvvp[nf * 64 + lane];
    }
    float vx[8], vy[8], vz[8];
#pragma unroll
    for (int j = 0; j < 8; j++) {
        int d = l4 * 8 + j;
        vx[j] = feat1o[(size_t)n * 96 + d * 3 + 0];
        vy[j] = feat1o[(size_t)n * 96 + d * 3 + 1];
        vz[j] = feat1o[(size_t)n * 96 + d * 3 + 2];
    }
    float bias[3][4];
#pragma unroll
    for (int nf = 0; nf < 4; nf++) {
        bias[0][nf] = b1[nf * 16 + l16];
        bias[1][nf] = b2[nf * 16 + l16];
        bias[2][nf] = b3[nf * 16 + l16];
    }

    unsigned short* x = xch[w];
    const int ntile = (deg + 15) >> 4;
    const int sw16 = (l16 & 7) << 3;

    for (int t = 0; t < ntile; ++t) {
        const int r0 = t * 16;
        int rowc = r0 + l16; if (rowc > deg - 1) rowc = deg - 1;   // clamped read row
        const int pe = peP[base + rowc];
        const int dd = dstP[base + rowc];
        const float rel0 = pos[dd * 3 + 0] - pn0;
        const float rel1 = pos[dd * 3 + 1] - pn1;
        const float rel2 = pos[dd * 3 + 2] - pn2;

        // ---- MLP (16 rows) ----
        half8 af[2];
        {
            const float* ap = edge_attr + (size_t)pe * 64 + l4 * 8;
            af[0] = pack8(*(const float4*)ap, *(const float4*)(ap + 4));
            af[1] = pack8(*(const float4*)(ap + 32), *(const float4*)(ap + 36));
        }
#pragma unroll
        for (int layer = 0; layer < 3; ++layer) {
            f32x4 acc[4];
#pragma unroll
            for (int nf = 0; nf < 4; nf++) acc[nf] = (f32x4){0.f,0.f,0.f,0.f};
#pragma unroll
            for (int kf = 0; kf < 2; kf++)
#pragma unroll
                for (int nf = 0; nf < 4; nf++)
                    acc[nf] = __builtin_amdgcn_mfma_f32_16x16x32_f16(
                        af[kf], wml[(layer * 8 + kf * 4 + nf) * 64 + lane],
                        acc[nf], 0, 0, 0);
#pragma unroll
            for (int nf = 0; nf < 4; nf++)
#pragma unroll
                for (int reg = 0; reg < 4; reg++) {
                    int row = l4 * 4 + reg;
                    int col = nf * 16 + l16;
                    float v = acc[nf][reg] + bias[layer][nf];
                    if (layer < 2) v = silu_f(v);
                    x[row * 64 + (col ^ ((row & 7) << 3))] = h2u((_Float16)v);
                }
            if (layer < 2) {
#pragma unroll
                for (int kf = 0; kf < 2; kf++)
                    af[kf] = *(const half8*)&x[l16 * 64 + ((kf * 32 + l4 * 8) ^ sw16)];
            }
        }
        half8 esf[2];
#pragma unroll
        for (int kf = 0; kf < 2; kf++)
            esf[kf] = *(const half8*)&x[l16 * 64 + ((kf * 32 + l4 * 8) ^ sw16)];

        // ---- ss consume (G in regs) + dotv ----
        f32x4 acc[4];
#pragma unroll
        for (int nf = 0; nf < 4; nf++) acc[nf] = (f32x4){0.f,0.f,0.f,0.f};
#pragma unroll
        for (int kf = 0; kf < 2; kf++)
#pragma unroll
            for (int nf = 0; nf < 4; nf++)
                acc[nf] = __builtin_amdgcn_mfma_f32_16x16x32_f16(
                    esf[kf], Gr[kf * 4 + nf], acc[nf], 0, 0, 0);
        half8 dvf;
#pragma unroll
        for (int j = 0; j < 8; j++)
            dvf[j] = (_Float16)(vx[j] * rel0 + vy[j] * rel1 + vz[j] * rel2);
#pragma unroll
        for (int nf = 0; nf < 4; nf++)
            acc[nf] = __builtin_amdgcn_mfma_f32_16x16x32_f16(
                dvf, wvvf[nf], acc[nf], 0, 0, 0);

        // ---- store via exchange to dst-sorted rows ----
#pragma unroll
        for (int nf = 0; nf < 4; nf++)
#pragma unroll
            for (int reg = 0; reg < 4; reg++) {
                int row = l4 * 4 + reg;
                int col = nf * 16 + l16;
                x[row * 64 + (col ^ ((row & 7) << 3))] = h2u((_Float16)acc[nf][reg]);
            }
#pragma unroll
        for (int i = 0; i < 2; i++) {
            int row16 = i * 8 + (lane >> 3);
            if (r0 + row16 < deg) {
                int rowD = pdP[base + r0 + row16];
                int c8 = lane & 7;
                half8 v = *(const half8*)&x[row16 * 64 + ((c8 * 8) ^ ((row16 & 7) << 3))];
                *(half8*)(msg0 + (size_t)rowD * 64 + c8 * 8) = v;
            }
        }
    }
}

// ---------------------------------------------------------------------------
// r4 msg0e (middle tier, verified).
__global__ __launch_bounds__(256, 2) void msg0e_r4_kernel(
    const float* __restrict__ feat0e,
    const float* __restrict__ feat1o,
    const float* __restrict__ edge_attr,
    const float* __restrict__ pos,
    const float* __restrict__ b1, const float* __restrict__ b2,
    const float* __restrict__ b3,
    const char* __restrict__ wsp,
    _Float16* __restrict__ msg0)
{
    __shared__ unsigned short st[4][4096];
    __shared__ unsigned short wf[16384];
    __shared__ float rell[4][64][3];
    __shared__ int   srcl[4][64];
    __shared__ int   pel[4][64];

    const int tid = threadIdx.x, w = tid >> 6, lane = tid & 63;
    const int l4 = lane >> 4, l16 = lane & 15;
    const long i0 = (long)blockIdx.x * 256 + w * 64;

    {
        long p = i0 + lane;
        int s_ = ((const int*)(wsp + OFF_SRCA))[p];
        int d_ = ((const int*)(wsp + OFF_DSTA))[p];
        pel[w][lane] = ((const int*)(wsp + OFF_PE))[p];
        srcl[w][lane] = s_;
        rell[w][lane][0] = pos[d_ * 3 + 0] - pos[s_ * 3 + 0];
        rell[w][lane][1] = pos[d_ * 3 + 1] - pos[s_ * 3 + 1];
        rell[w][lane][2] = pos[d_ * 3 + 2] - pos[s_ * 3 + 2];
    }
    __syncthreads();

    half8 esf[4][2];
    mlp_wave(edge_attr, b1, b2, b3, wsp, pel[w], st[w], lane, esf);
    __syncthreads();

#pragma unroll
    for (int r4 = 0; r4 < 4; r4++) {
        int row = r4 * 16 + (lane >> 2);
        int ch = lane & 3;
        const float* sp = feat0e + (size_t)srcl[w][row] * 64 + ch * 16;
        half8 h0 = pack8(*(const float4*)(sp + 0), *(const float4*)(sp + 4));
        half8 h1 = pack8(*(const float4*)(sp + 8), *(const float4*)(sp + 12));
        int r7 = row & 7;
        *(half8*)&st[w][row * 64 + (((ch * 2) ^ r7) * 8)]     = h0;
        *(half8*)&st[w][row * 64 + (((ch * 2 + 1) ^ r7) * 8)] = h1;
    }
    __syncthreads();

    f32x4 acc[4][4];
#pragma unroll
    for (int mf = 0; mf < 4; mf++)
#pragma unroll
        for (int nf = 0; nf < 4; nf++) acc[mf][nf] = (f32x4){0.f, 0.f, 0.f, 0.f};

    const half8* wss_g = (const half8*)(wsp + OFF_WSS);
    half8* wfh = (half8*)wf;
    for (int pc = 0; pc < 16; ++pc) {
        __syncthreads();
#pragma unroll
        for (int q = 0; q < 8; q++)
            wfh[q * 256 + tid] = wss_g[pc * 2048 + q * 256 + tid];
        __syncthreads();
#pragma unroll
        for (int pl = 0; pl < 4; ++pl) {
            const int p = pc * 4 + pl;
            _Float16 sv[4];
#pragma unroll
            for (int mf = 0; mf < 4; mf++) {
                int row = mf * 16 + l16;
                sv[mf] = u2h(st[w][row * 64 + (((p >> 3) ^ (row & 7)) * 8) + (p & 7)]);
            }
#pragma unroll
            for (int kf = 0; kf < 2; kf++) {
                half8 bf[4];
#pragma unroll
                for (int nf = 0; nf < 4; nf++)
                    bf[nf] = wfh[(pl * 8 + kf * 4 + nf) * 64 + lane];
#pragma unroll
                for (int mf = 0; mf < 4; mf++) {
                    half8 a = esf[mf][kf] * sv[mf];
#pragma unroll
                    for (int nf = 0; nf < 4; nf++)
                        acc[mf][nf] = __builtin_amdgcn_mfma_f32_16x16x32_f16(a, bf[nf], acc[mf][nf], 0, 0, 0);
                }
            }
        }
    }

    half8 dvf[4];
#pragma unroll
    for (int mf = 0; mf < 4; mf++) {
        int row = mf * 16 + l16;
        int se = srcl[w][row];
        float r0 = rell[w][row][0], r1 = rell[w][row][1], r2 = rell[w][row][2];
        const float* vp = feat1o + (size_t)se * 96 + l4 * 24;
        float4 A = *(const float4*)(vp + 0),  B = *(const float4*)(vp + 4);
        float4 C = *(const float4*)(vp + 8),  D = *(const float4*)(vp + 12);
        float4 E = *(const float4*)(vp + 16), F = *(const float4*)(vp + 20);
        dvf[mf][0] = (_Float16)(A.x * r0 + A.y * r1 + A.z * r2);
        dvf[mf][1] = (_Float16)(A.w * r0 + B.x * r1 + B.y * r2);
        dvf[mf][2] = (_Float16)(B.z * r0 + B.w * r1 + C.x * r2);
        dvf[mf][3] = (_Float16)(C.y * r0 + C.z * r1 + C.w * r2);
        dvf[mf][4] = (_Float16)(D.x * r0 + D.y * r1 + D.z * r2);
        dvf[mf][5] = (_Float16)(D.w * r0 + E.x * r1 + E.y * r2);
        dvf[mf][6] = (_Float16)(E.z * r0 + E.w * r1 + F.x * r2);
        dvf[mf][7] = (_Float16)(F.y * r0 + F.z * r1 + F.w * r2);
    }
    const half8* wvvp = (const half8*)(wsp + OFF_WVV);
#pragma unroll
    for (int nf = 0; nf < 4; nf++) {
        half8 bvv = wvvp[nf * 64 + lane];
#pragma unroll
        for (int mf = 0; mf < 4; mf++)
            acc[mf][nf] = __builtin_amdgcn_mfma_f32_16x16x32_f16(dvf[mf], bvv, acc[mf][nf], 0, 0, 0);
    }

#pragma unroll
    for (int mf = 0; mf < 4; mf++)
#pragma unroll
        for (int nf = 0; nf < 4; nf++)
#pragma unroll
            for (int reg = 0; reg < 4; reg++) {
                int row = mf * 16 + l4 * 4 + reg;
                int col = nf * 16 + l16;
                st[w][row * 64 + (col ^ ((row & 7) << 3))] = h2u((_Float16)acc[mf][nf][reg]);
            }
#pragma unroll
    for (int t = 0; t < 8; t++) {
        int row = t * 8 + (lane >> 3);
        int c8 = lane & 7;
        half8 v = *(const half8*)&st[w][row * 64 + ((c8 * 8) ^ ((row & 7) << 3))];
        *(half8*)(msg0 + (size_t)(i0 + row) * 64 + c8 * 8) = v;
    }
}

// ---------------------------------------------------------------------------
// msg1o (dst-sorted, verified r4/r5).
__global__ __launch_bounds__(256, 2) void msg1o_kernel(
    const float* __restrict__ feat0e,
    const float* __restrict__ feat1o,
    const float* __restrict__ edge_attr,
    const float* __restrict__ pos,
    const float* __restrict__ b1, const float* __restrict__ b2,
    const float* __restrict__ b3,
    const char* __restrict__ wsp,
    _Float16* __restrict__ msg1)
{
    __shared__ unsigned short vt[4][6144];
    __shared__ float rell[4][64][3];
    __shared__ int srcl[4][64];
    __shared__ int pel[4][64];

    const int tid = threadIdx.x, w = tid >> 6, lane = tid & 63;
    const int l4 = lane >> 4, l16 = lane & 15;
    const long i0 = (long)blockIdx.x * 256 + w * 64;

    {
        long p = i0 + lane;
        int s_ = ((const int*)(wsp + OFF_SRCA))[p];
        int d_ = ((const int*)(wsp + OFF_DSTA))[p];
        pel[w][lane] = ((const int*)(wsp + OFF_PE))[p];
        srcl[w][lane] = s_;
        rell[w][lane][0] = pos[d_ * 3 + 0] - pos[s_ * 3 + 0];
        rell[w][lane][1] = pos[d_ * 3 + 1] - pos[s_ * 3 + 1];
        rell[w][lane][2] = pos[d_ * 3 + 2] - pos[s_ * 3 + 2];
    }
    __syncthreads();

    half8 esf[4][2];
    mlp_wave(edge_attr, b1, b2, b3, wsp, pel[w], vt[w], lane, esf);
    __syncthreads();

    {
        const float* vp = feat1o + (size_t)srcl[w][lane] * 96;
#pragma unroll
        for (int q = 0; q < 24; q++) {
            float4 f = *(const float4*)(vp + q * 4);
            vt[w][(q * 4 + 0) * 64 + lane] = h2u((_Float16)f.x);
            vt[w][(q * 4 + 1) * 64 + lane] = h2u((_Float16)f.y);
            vt[w][(q * 4 + 2) * 64 + lane] = h2u((_Float16)f.z);
            vt[w][(q * 4 + 3) * 64 + lane] = h2u((_Float16)f.w);
        }
    }
    __syncthreads();

    const half8* wvs2p = (const half8*)(wsp + OFF_WVS2);
    const half8* wsvp  = (const half8*)(wsp + OFF_WSV);
    const half8* wxp   = (const half8*)(wsp + OFF_WX);

    f32x4 acc1[4][3][2];
#pragma unroll
    for (int g = 0; g < 4; g++)
#pragma unroll
        for (int x = 0; x < 3; x++)
#pragma unroll
            for (int ch = 0; ch < 2; ch++) acc1[g][x][ch] = (f32x4){0.f,0.f,0.f,0.f};

#pragma unroll 2
    for (int ck = 0; ck < 16; ++ck) {
        half8 bf[2][4];
#pragma unroll
        for (int kf = 0; kf < 2; kf++)
#pragma unroll
            for (int nfl = 0; nfl < 4; nfl++)
                bf[kf][nfl] = wvs2p[(ck * 8 + kf * 4 + nfl) * 64 + lane];
#pragma unroll
        for (int g = 0; g < 4; g++) {
            f32x4 tacc[4];
#pragma unroll
            for (int nfl = 0; nfl < 4; nfl++) tacc[nfl] = (f32x4){0.f,0.f,0.f,0.f};
#pragma unroll
            for (int kf = 0; kf < 2; kf++)
#pragma unroll
                for (int nfl = 0; nfl < 4; nfl++)
                    tacc[nfl] = __builtin_amdgcn_mfma_f32_16x16x32_f16(
                        esf[g][kf], bf[kf][nfl], tacc[nfl], 0, 0, 0);
#pragma unroll
            for (int dl = 0; dl < 2; dl++) {
                int d = ck * 2 + dl;
#pragma unroll
                for (int x = 0; x < 3; x++) {
                    half4 hv = *(const half4*)&vt[w][(d * 3 + x) * 64 + g * 16 + l4 * 4];
                    f32x4 vf = __builtin_convertvector(hv, f32x4);
                    acc1[g][x][0] += vf * tacc[dl * 2 + 0];
                    acc1[g][x][1] += vf * tacc[dl * 2 + 1];
                }
            }
        }
    }

    {
        half8 bsv[2][2];
#pragma unroll
        for (int kf = 0; kf < 2; kf++)
#pragma unroll
            for (int nf = 0; nf < 2; nf++)
                bsv[kf][nf] = wsvp[(size_t)(kf * 2 + nf) * 64 + lane];
#pragma unroll
        for (int g = 0; g < 4; g++) {
            int erow = g * 16 + l16;
            const float* sp = feat0e + (size_t)srcl[w][erow] * 64 + l4 * 8;
            half8 sf[2];
#pragma unroll
            for (int kf = 0; kf < 2; kf++)
                sf[kf] = pack8(*(const float4*)(sp + kf * 32),
                               *(const float4*)(sp + kf * 32 + 4));
#pragma unroll
            for (int x = 0; x < 3; x++) {
                _Float16 rl = (_Float16)rell[w][erow][x];
#pragma unroll
                for (int kf = 0; kf < 2; kf++) {
                    half8 a = sf[kf] * rl;
#pragma unroll
                    for (int nf = 0; nf < 2; nf++)
                        acc1[g][x][nf] = __builtin_amdgcn_mfma_f32_16x16x32_f16(
                            a, bsv[kf][nf], acc1[g][x][nf], 0, 0, 0);
                }
            }
        }
    }

    {
        half8 bx[2];
        bx[0] = wxp[lane];
        bx[1] = wxp[64 + lane];
#pragma unroll
        for (int g = 0; g < 4; g++) {
            f32x4 cx[3][2];
#pragma unroll
            for (int xp = 0; xp < 3; xp++) {
                half8 av;
#pragma unroll
                for (int j = 0; j < 8; j++)
                    av[j] = u2h(vt[w][((l4 * 8 + j) * 3 + xp) * 64 + g * 16 + l16]);
#pragma unroll
                for (int nf = 0; nf < 2; nf++)
                    cx[xp][nf] = __builtin_amdgcn_mfma_f32_16x16x32_f16(
                        av, bx[nf], (f32x4){0.f,0.f,0.f,0.f}, 0, 0, 0);
            }
            f32x4 r[3];
#pragma unroll
            for (int x = 0; x < 3; x++)
#pragma unroll
                for (int reg = 0; reg < 4; reg++)
                    r[x][reg] = rell[w][g * 16 + l4 * 4 + reg][x];
#pragma unroll
            for (int x = 0; x < 3; x++) {
                const int x1 = (x + 1) % 3, x2 = (x + 2) % 3;
#pragma unroll
                for (int ch = 0; ch < 2; ch++)
                    acc1[g][x][ch] += r[x2] * cx[x1][ch] - r[x1] * cx[x2][ch];
            }
        }
    }

    __syncthreads();
#pragma unroll
    for (int g = 0; g < 4; g++)
#pragma unroll
        for (int reg = 0; reg < 4; reg++) {
            int row = g * 16 + l4 * 4 + reg;
            int sw = (row & 3) << 3;
#pragma unroll
            for (int x = 0; x < 3; x++)
#pragma unroll
                for (int ch = 0; ch < 2; ch++) {
                    int c32 = ch * 16 + l16;
                    vt[w][row * 96 + x * 32 + (c32 ^ sw)] = h2u((_Float16)acc1[g][x][ch][reg]);
                }
        }
#pragma unroll
    for (int tt = 0; tt < 12; tt++) {
        int x = tt >> 2, rem = (tt & 3) * 8;
        int col = x * 32 + (rem ^ ((lane & 3) << 3));
        half8 v = *(const half8*)&vt[w][lane * 96 + col];
        *(half8*)(msg1 + (size_t)(i0 + lane) * 96 + tt * 8) = v;
    }
}

// ---------------------------------------------------------------------------
// gather0 (contiguous dst ranges; used by BOTH tiers now).
__global__ __launch_bounds__(256) void gather0_kernel(
    const float* __restrict__ feat0e,
    const float* __restrict__ Wg, const float* __restrict__ bg,
    const char* __restrict__ wsp, const _Float16* __restrict__ msg0,
    float* __restrict__ out)
{
    __shared__ float Wgl[2048];
    __shared__ float ag[4][64];
    const int tid = threadIdx.x, w = tid >> 6, lane = tid & 63;
    for (int t = tid; t < 2048; t += 256) Wgl[t] = Wg[t];

    const int n = blockIdx.x * 4 + w;
    const int* rs = (const int*)(wsp + OFF_RS);
    const int i0 = rs[n], i1 = rs[n + 1];
    const int r8 = lane >> 3, c8 = lane & 7;

    float a[8];
#pragma unroll
    for (int j = 0; j < 8; j++) a[j] = 0.f;
    for (int i = i0 + r8; i < i1; i += 8) {
        half8 m = *(const half8*)(msg0 + (size_t)i * 64 + c8 * 8);
#pragma unroll
        for (int j = 0; j < 8; j++) a[j] += (float)m[j];
    }
#pragma unroll
    for (int s = 8; s < 64; s <<= 1)
#pragma unroll
        for (int j = 0; j < 8; j++) a[j] += __shfl_xor(a[j], s);
    if (r8 == 0)
#pragma unroll
        for (int j = 0; j < 8; j++) ag[w][c8 * 8 + j] = a[j];
    __syncthreads();

    const float inv = 1.0f / fmaxf((float)(i1 - i0), 1.0f);
    float av = ag[w][lane] * inv;
    out[(size_t)n * 160 + lane] = silu_f(av) + feat0e[(size_t)n * 64 + lane];

    if (lane < 32) {
        float gs = bg[lane];
#pragma unroll
        for (int p = 0; p < 64; ++p) gs = fmaf(ag[w][p] * inv, Wgl[p * 32 + lane], gs);
        out[(size_t)n * 160 + 64 + lane] = silu_f(gs);
    }
}

// ---------------------------------------------------------------------------
__global__ __launch_bounds__(256) void gather1_kernel(
    const float* __restrict__ feat1o,
    const char* __restrict__ wsp, const _Float16* __restrict__ msg1,
    float* __restrict__ out)
{
    __shared__ float ag1[4][96];
    __shared__ float gl[4][32];
    const int tid = threadIdx.x, w = tid >> 6, lane = tid & 63;
    const int n = blockIdx.x * 4 + w;
    const int* rs = (const int*)(wsp + OFF_RS);
    const int i0 = rs[n], i1 = rs[n + 1];

    if (lane < 32) gl[w][lane] = out[(size_t)n * 160 + 64 + lane];

    const int r4 = lane >> 4, c12 = lane & 15;
    float a[8];
#pragma unroll
    for (int j = 0; j < 8; j++) a[j] = 0.f;
    if (c12 < 12)
        for (int i = i0 + r4; i < i1; i += 4) {
            half8 m = *(const half8*)(msg1 + (size_t)i * 96 + c12 * 8);
#pragma unroll
            for (int j = 0; j < 8; j++) a[j] += (float)m[j];
        }
#pragma unroll
    for (int s = 16; s < 64; s <<= 1)
#pragma unroll
        for (int j = 0; j < 8; j++) a[j] += __shfl_xor(a[j], s);
    if (r4 == 0 && c12 < 12)
#pragma unroll
        for (int j = 0; j < 8; j++) ag1[w][c12 * 8 + j] = a[j];
    __syncthreads();

    const float inv = 1.0f / fmaxf((float)(i1 - i0), 1.0f);
#pragma unroll
    for (int t = 0; t < 2; t++) {
        int idx = t * 64 + lane;
        if (idx < 96) {
            int c = idx / 3, x = idx - 3 * c;
            float v = ag1[w][x * 32 + c] * inv * gl[w][c] + feat1o[(size_t)n * 96 + idx];
            out[(size_t)n * 160 + 64 + idx] = v;
        }
    }
}

// ---------------------------------------------------------------------------
extern "C" void kernel_launch(void* const* d_in, const int* in_sizes, int n_in,
                              void* d_out, int out_size, void* d_ws, size_t ws_size,
                              hipStream_t stream) {
    const float* feat0e    = (const float*)d_in[0];
    const float* feat1o    = (const float*)d_in[1];
    const float* edge_attr = (const float*)d_in[2];
    const float* pos       = (const float*)d_in[3];
    const int*   eidx      = (const int*)d_in[4];
    const float* W1 = (const float*)d_in[5];
    const float* b1 = (const float*)d_in[6];
    const float* W2 = (const float*)d_in[7];
    const float* b2 = (const float*)d_in[8];
    const float* W3 = (const float*)d_in[9];
    const float* b3 = (const float*)d_in[10];
    const float* wss    = (const float*)d_in[11];
    const float* wvv    = (const float*)d_in[12];
    const float* wsv    = (const float*)d_in[13];
    const float* wvs    = (const float*)d_in[14];
    const float* wcross = (const float*)d_in[15];
    const float* Wg = (const float*)d_in[16];
    const float* bg = (const float*)d_in[17];

    float* out = (float*)d_out;
    char*  ws  = (char*)d_ws;
    int* hist = (int*)(ws + OFF_HIST);
    int* rs   = (int*)(ws + OFF_RS);
    int* cur  = (int*)(ws + OFF_CUR);
    int* flag = (int*)(ws + OFF_FLAG);
    int* srca = (int*)(ws + OFF_SRCA);
    int* dsta = (int*)(ws + OFF_DSTA);
    int* pe   = (int*)(ws + OFF_PE);
    _Float16* msg = (_Float16*)(ws + OFF_MSG);

    detect_idx_kernel<<<1, 1, 0, stream>>>(eidx, flag);
    hipMemsetAsync(ws + OFF_HIST, 0, NN * sizeof(int), stream);

    int S = 0;
    if (ws_size >= NEED_S(20000)) S = 1;
    else if (ws_size >= NEED_S(10000)) S = 2;
    else if (ws_size >= NEED_S(5000))  S = 4;
    else if (ws_size >= NEED_S(2500))  S = 8;

    if (S > 0) {
        int* outd = (int*)(ws + OFF_OUTD);
        int* psP  = (int*)(ws + OFF_PSP);
        int* curS = (int*)(ws + OFF_CURS);
        int* dstP = (int*)(ws + OFF_DSTP);
        int* peP  = (int*)(ws + OFF_PEP);
        int* pdP  = (int*)(ws + OFF_PDP);
        _Float16* G = (_Float16*)(ws + OFF_G);

        hipMemsetAsync(ws + OFF_OUTD, 0, NN * sizeof(int), stream);

        hist2_kernel<<<EE / 256, 256, 0, stream>>>(eidx, flag, hist, outd);
        scan_kernel<<<1, 1024, 0, stream>>>(hist, rs, cur);
        scanP_kernel<<<1, 1024, 0, stream>>>(outd, psP, curS);
        scat_both_kernel<<<EE / 256, 256, 0, stream>>>(
            eidx, flag, curS, cur, dstP, peP, pdP, srca, dsta, pe);
        prep_kernel<<<(75904 + 255) / 256, 256, 0, stream>>>(
            wss, wvv, wsv, wvs, wcross, W1, W2, W3, ws, 75904);

        const int npp = (NN + S - 1) / S;
        for (int s = 0; s < S; ++s) {
            int lo = s * npp;
            int hi = lo + npp; if (hi > NN) hi = NN;
            gG_kernel<<<(hi - lo + 63) / 64, 256, 0, stream>>>(
                feat0e, (const char*)ws, lo, hi, G);
            msg0e_node_kernel<<<(hi - lo + 3) / 4, 256, 0, stream>>>(
                feat1o, edge_attr, pos, b1, b2, b3, (const char*)ws, G, lo, hi, msg);
        }
        gather0_kernel<<<NN / 4, 256, 0, stream>>>(
            feat0e, Wg, bg, (const char*)ws, msg, out);
        msg1o_kernel<<<EE / 256, 256, 0, stream>>>(
            feat0e, feat1o, edge_attr, pos, b1, b2, b3, (const char*)ws, msg);
        gather1_kernel<<<NN / 4, 256, 0, stream>>>(
            feat1o, (const char*)ws, msg, out);
    } else {
        // middle tier: round-4 proven path
        hist_kernel<<<EE / 256, 256, 0, stream>>>(eidx, flag, hist);
        scan_kernel<<<1, 1024, 0, stream>>>(hist, rs, cur);
        scatter_r4_kernel<<<EE / 256, 256, 0, stream>>>(eidx, flag, cur, srca, dsta, pe);
        prep_kernel<<<(43136 + 255) / 256, 256, 0, stream>>>(
            wss, wvv, wsv, wvs, wcross, W1, W2, W3, ws, 43136);
        msg0e_r4_kernel<<<EE / 256, 256, 0, stream>>>(
            feat0e, feat1o, edge_attr, pos, b1, b2, b3, (const char*)ws, msg);
        gather0_kernel<<<NN / 4, 256, 0, stream>>>(
            feat0e, Wg, bg, (const char*)ws, msg, out);
        msg1o_kernel<<<EE / 256, 256, 0, stream>>>(
            feat0e, feat1o, edge_attr, pos, b1, b2, b3, (const char*)ws, msg);
        gather1_kernel<<<NN / 4, 256, 0, stream>>>(
            feat1o, (const char*)ws, msg, out);
    }
}

// Round 7
// 798.448 us; speedup vs baseline: 1.3270x; 1.0640x over previous
//
#include <hip/hip_runtime.h>

// EquivariantConvLayer — Round 7.
// Fused node-wave kernel msg01_node: per src-node wave holds G[n] (32 VGPR),
// H[n] (48 VGPR, vs-path factor), g/CXW (LDS); per 16-edge tile: MLP(24 MFMA,
// computed ONCE) -> msg0 (es@G + dotv, 12 MFMA) -> msg1 (es@H, 12 MFMA +
// VALU sv/cross epilogue). New gH kernel: H = TTV(v, wvs) + CXW via MFMA.
// Fallback: complete verified r6 pipeline when ws is too small.

#define NN 20000
#define EE 640000
#define D0 64
#define D1 32
#define HH 64
#define EPMAX 940032

typedef _Float16 half8 __attribute__((ext_vector_type(8)));
typedef _Float16 half4 __attribute__((ext_vector_type(4)));
typedef float f32x4 __attribute__((ext_vector_type(4)));

__device__ __forceinline__ float silu_f(float x) { return x / (1.0f + __expf(-x)); }
__device__ __forceinline__ _Float16 u2h(unsigned short u) {
    union { unsigned short u; _Float16 h; } c; c.u = u; return c.h;
}
__device__ __forceinline__ unsigned short h2u(_Float16 h) {
    union { unsigned short u; _Float16 h; } c; c.h = h; return c.u;
}
__device__ __forceinline__ half8 pack8(float4 a, float4 b) {
    half8 h;
    h[0]=(_Float16)a.x; h[1]=(_Float16)a.y; h[2]=(_Float16)a.z; h[3]=(_Float16)a.w;
    h[4]=(_Float16)b.x; h[5]=(_Float16)b.y; h[6]=(_Float16)b.z; h[7]=(_Float16)b.w;
    return h;
}

// ---- shared low region (both layouts) ----
#define OFF_HIST  0ull
#define OFF_RS    81920ull
#define OFF_CUR   163840ull
#define OFF_FLAG  245760ull
// ---- old (r6 fallback) layout ----
#define OFF_SRCA  262144ull
#define OFF_DSTA  2822144ull
#define OFF_PE    5382144ull
#define OFF_WSS   7942144ull
#define OFF_WVS2  8466432ull
#define OFF_WVV   8597504ull
#define OFF_WSV   8601600ull
#define OFF_WX    8605696ull
#define OFF_WMLP  8607744ull
#define OFF_MSG   8632320ull
#define OFF_WSSG  131512320ull
#define OFF_OUTD  132036608ull
#define OFF_PSP   132118528ull
#define OFF_CURS  132200448ull
#define OFF_DSTP  132282368ull
#define OFF_PEP   136042496ull
#define OFF_PDP   139802624ull
#define OFF_G     143562752ull
#define NEED_S(npp) (OFF_G + (unsigned long long)(npp) * 8192ull)
// ---- new fused layout ----
#define F_OUTD  262144ull
#define F_PSP   360448ull
#define F_CURS  458752ull
#define F_AUX   557056ull        // NN*256B f16: [0..31]=g, [32+x*32+c]=CXW
#define F_DSTP  5677056ull
#define F_PEP   9437184ull
#define F_PDP   13197312ull
#define F_WMLP  16957440ull
#define F_WVV   16982016ull
#define F_WSV   16986112ull
#define F_WX2   16990208ull
#define F_WSSG  16992256ull
#define F_WVS3  17516544ull
#define F_MSG0  17647616ull      // E*128B
#define F_MSG1  99567616ull      // E*192B
#define F_GH    222447616ull     // npp*20480B: per node G(8192B)+H(12288B)
#define NEED_F(npp) (F_GH + (unsigned long long)(npp) * 20480ull)

// ---------------------------------------------------------------------------
__global__ void detect_idx_kernel(const int* __restrict__ eidx, int* __restrict__ flag) {
    int odd_nz = 0, even_nz = 0;
    for (int k = 0; k < 64; ++k) {
        if (eidx[2 * k + 1] != 0) odd_nz = 1;
        if (eidx[2 * k] != 0) even_nz = 1;
    }
    *flag = (!odd_nz && even_nz) ? 1 : 0;
}

__device__ __forceinline__ void load_sd(const int* eidx, const int* flag, int e,
                                        int& s_, int& d_) {
    if (*flag) { s_ = (int)((const long long*)eidx)[e]; d_ = (int)((const long long*)eidx)[EE + e]; }
    else       { s_ = eidx[e];                          d_ = eidx[EE + e]; }
}

__global__ __launch_bounds__(256) void hist2_kernel(
    const int* __restrict__ eidx, const int* __restrict__ flag,
    int* __restrict__ hist, int* __restrict__ outd)
{
    const int e = blockIdx.x * 256 + threadIdx.x;
    int s_, d_; load_sd(eidx, flag, e, s_, d_);
    atomicAdd(hist + d_, 1);
    atomicAdd(outd + s_, 1);
}

__global__ __launch_bounds__(1024) void scan_kernel(
    const int* __restrict__ hist, int* __restrict__ rs, int* __restrict__ cur)
{
    __shared__ int part[1024];
    const int t = threadIdx.x;
    const int base = t * 20;
    int loc[20];
    int tot = 0;
#pragma unroll
    for (int k = 0; k < 20; ++k) {
        int n = base + k;
        int h = (n < NN) ? hist[n] : 0;
        loc[k] = tot; tot += h;
    }
    part[t] = tot;
    __syncthreads();
    for (int off = 1; off < 1024; off <<= 1) {
        int v = (t >= off) ? part[t - off] : 0;
        __syncthreads();
        part[t] += v;
        __syncthreads();
    }
    int excl = part[t] - tot;
#pragma unroll
    for (int k = 0; k < 20; ++k) {
        int n = base + k;
        if (n < NN) { rs[n] = excl + loc[k]; cur[n] = excl + loc[k]; }
    }
    if (t == 1023) rs[NN] = part[1023];
}

__global__ __launch_bounds__(1024) void scanP_kernel(
    const int* __restrict__ outd, int* __restrict__ psP, int* __restrict__ curS)
{
    __shared__ int part[1024];
    const int t = threadIdx.x;
    const int base = t * 20;
    int loc[20];
    int tot = 0;
#pragma unroll
    for (int k = 0; k < 20; ++k) {
        int n = base + k;
        int p = (n < NN) ? ((outd[n] + 15) & ~15) : 0;
        loc[k] = tot; tot += p;
    }
    part[t] = tot;
    __syncthreads();
    for (int off = 1; off < 1024; off <<= 1) {
        int v = (t >= off) ? part[t - off] : 0;
        __syncthreads();
        part[t] += v;
        __syncthreads();
    }
    int excl = part[t] - tot;
#pragma unroll
    for (int k = 0; k < 20; ++k) {
        int n = base + k;
        if (n < NN) { psP[n] = excl + loc[k]; curS[n] = excl + loc[k]; }
    }
}

// fused-path scatter: src-padded order + link to dst-order rows.
__global__ __launch_bounds__(256) void scat_src_kernel(
    const int* __restrict__ eidx, const int* __restrict__ flag,
    int* __restrict__ curS, int* __restrict__ cur,
    int* __restrict__ dstP, int* __restrict__ peP, int* __restrict__ pdP)
{
    const int e = blockIdx.x * 256 + threadIdx.x;
    int s_, d_; load_sd(eidx, flag, e, s_, d_);
    int posS = atomicAdd(curS + s_, 1);
    int posD = atomicAdd(cur + d_, 1);
    dstP[posS] = d_; peP[posS] = e; pdP[posS] = posD;
}

// old-path scatter (fallback)
__global__ __launch_bounds__(256) void scat_both_kernel(
    const int* __restrict__ eidx, const int* __restrict__ flag,
    int* __restrict__ curS, int* __restrict__ cur,
    int* __restrict__ dstP, int* __restrict__ peP, int* __restrict__ pdP,
    int* __restrict__ srca, int* __restrict__ dsta, int* __restrict__ pe)
{
    const int e = blockIdx.x * 256 + threadIdx.x;
    int s_, d_; load_sd(eidx, flag, e, s_, d_);
    int posS = atomicAdd(curS + s_, 1);
    int posD = atomicAdd(cur + d_, 1);
    dstP[posS] = d_; peP[posS] = e; pdP[posS] = posD;
    srca[posD] = s_; dsta[posD] = d_; pe[posD] = e;
}

// ---------------------------------------------------------------------------
// prep2: fused-path weight permutations.
__global__ __launch_bounds__(256) void prep2_kernel(
    const float* __restrict__ wss, const float* __restrict__ wvv,
    const float* __restrict__ wsv, const float* __restrict__ wvs,
    const float* __restrict__ wx,
    const float* __restrict__ W1, const float* __restrict__ W2,
    const float* __restrict__ W3, char* __restrict__ ws)
{
    int id = blockIdx.x * 256 + threadIdx.x;
    if (id >= 43136) return;
    int l = id & 63;
    int l4 = l >> 4, l16 = l & 15;
    half8 o;
    _Float16* dst;
    if (id < 32768) {                        // WSSG (G precompute B)
        int i = id;
        int f = i >> 6;
        int q = f >> 3, kfp = (f >> 2) & 1, nfp = f & 3;
#pragma unroll
        for (int j = 0; j < 8; j++) {
            int p = kfp * 32 + l4 * 8 + j;
            int cc = q * 64 + nfp * 16 + l16;
            int jc = cc & 7, lc = (cc >> 3) & 63, fi = cc >> 9;
            int kfc = fi >> 2, nfc = fi & 3;
            int h = kfc * 32 + (lc >> 4) * 8 + jc;
            int oo = nfc * 16 + (lc & 15);
            o[j] = (_Float16)wss[((size_t)p * 64 + h) * 64 + oo];
        }
        dst = (_Float16*)(ws + F_WSSG) + (size_t)i * 8;
    } else if (id < 40960) {                 // WVS3: B[d][col2048=h*32+c], K=32
        int i = id - 32768;
        int nf = i >> 6;
#pragma unroll
        for (int j = 0; j < 8; j++) {
            int d = l4 * 8 + j;
            int col = nf * 16 + l16;
            o[j] = (_Float16)wvs[((size_t)d * 64 + (col >> 5)) * 32 + (col & 31)];
        }
        dst = (_Float16*)(ws + F_WVS3) + (size_t)i * 8;
    } else if (id < 42496) {                 // WMLP
        int i = id - 40960; int f = i >> 6;
        int layer = f >> 3, kf = (f >> 2) & 1, nf = f & 3;
        const float* W = layer == 0 ? W1 : (layer == 1 ? W2 : W3);
#pragma unroll
        for (int j = 0; j < 8; j++)
            o[j] = (_Float16)W[(kf * 32 + l4 * 8 + j) * 64 + nf * 16 + l16];
        dst = (_Float16*)(ws + F_WMLP) + (size_t)i * 8;
    } else if (id < 42752) {                 // WVV
        int i = id - 42496; int nf = i >> 6;
#pragma unroll
        for (int j = 0; j < 8; j++)
            o[j] = (_Float16)wvv[(l4 * 8 + j) * 64 + nf * 16 + l16];
        dst = (_Float16*)(ws + F_WVV) + (size_t)i * 8;
    } else if (id < 43008) {                 // WSV
        int i = id - 42752; int frag = i >> 6;
        int kf = frag >> 1, nf = frag & 1;
#pragma unroll
        for (int j = 0; j < 8; j++)
            o[j] = (_Float16)wsv[(kf * 32 + l4 * 8 + j) * 32 + nf * 16 + l16];
        dst = (_Float16*)(ws + F_WSV) + (size_t)i * 8;
    } else {                                 // WX2: B[d][c], K=32
        int i = id - 43008; int nf = i >> 6;
#pragma unroll
        for (int j = 0; j < 8; j++)
            o[j] = (_Float16)wx[(l4 * 8 + j) * 32 + nf * 16 + l16];
        dst = (_Float16*)(ws + F_WX2) + (size_t)i * 8;
    }
    *(half8*)dst = o;
}

// ---------------------------------------------------------------------------
// gG2: G[n] = s@wss (frag-linear, stride 10240 f16) + g[n] = s@wsv into aux.
__global__ __launch_bounds__(256, 2) void gG2_kernel(
    const float* __restrict__ feat0e, const char* __restrict__ wsp,
    int lo, int hi, _Float16* __restrict__ GH, _Float16* __restrict__ aux)
{
    const int tid = threadIdx.x, w = tid >> 6, lane = tid & 63;
    const int l4 = lane >> 4, l16 = lane & 15;
    const int n0 = lo + blockIdx.x * 64 + w * 16;
    if (n0 >= hi) return;

    half8 af[2];
    {
        int n = n0 + l16; if (n >= NN) n = NN - 1;
        const float* sp = feat0e + (size_t)n * 64 + l4 * 8;
        af[0] = pack8(*(const float4*)sp, *(const float4*)(sp + 4));
        af[1] = pack8(*(const float4*)(sp + 32), *(const float4*)(sp + 36));
    }
    const half8* wg = (const half8*)(wsp + F_WSSG);
    for (int q = 0; q < 64; ++q) {
        f32x4 acc[4];
#pragma unroll
        for (int nf = 0; nf < 4; nf++) acc[nf] = (f32x4){0.f,0.f,0.f,0.f};
#pragma unroll
        for (int kf = 0; kf < 2; kf++)
#pragma unroll
            for (int nf = 0; nf < 4; nf++)
                acc[nf] = __builtin_amdgcn_mfma_f32_16x16x32_f16(
                    af[kf], wg[(q * 8 + kf * 4 + nf) * 64 + lane], acc[nf], 0, 0, 0);
#pragma unroll
        for (int nf = 0; nf < 4; nf++)
#pragma unroll
            for (int reg = 0; reg < 4; reg++) {
                int n = n0 + l4 * 4 + reg;
                if (n < hi && n < NN)
                    GH[(size_t)(n - lo) * 10240 + q * 64 + nf * 16 + l16] =
                        (_Float16)acc[nf][reg];
            }
    }
    // g = s @ wsv
    {
        const half8* wsvp = (const half8*)(wsp + F_WSV);
        f32x4 accg[2];
#pragma unroll
        for (int nf = 0; nf < 2; nf++) accg[nf] = (f32x4){0.f,0.f,0.f,0.f};
#pragma unroll
        for (int kf = 0; kf < 2; kf++)
#pragma unroll
            for (int nf = 0; nf < 2; nf++)
                accg[nf] = __builtin_amdgcn_mfma_f32_16x16x32_f16(
                    af[kf], wsvp[(kf * 2 + nf) * 64 + lane], accg[nf], 0, 0, 0);
#pragma unroll
        for (int nf = 0; nf < 2; nf++)
#pragma unroll
            for (int reg = 0; reg < 4; reg++) {
                int n = n0 + l4 * 4 + reg;
                if (n < hi && n < NN)
                    aux[(size_t)n * 128 + nf * 16 + l16] = (_Float16)accg[nf][reg];
            }
    }
}

// ---------------------------------------------------------------------------
// gH: H[n][x][h*32+c] = sum_d v[n,d,x]*wvs[d,h,c]; CXW[n][x][c] into aux.
__global__ __launch_bounds__(256, 2) void gH_kernel(
    const float* __restrict__ feat1o, const char* __restrict__ wsp,
    int lo, int hi, _Float16* __restrict__ GH, _Float16* __restrict__ aux)
{
    const int tid = threadIdx.x, w = tid >> 6, lane = tid & 63;
    const int l4 = lane >> 4, l16 = lane & 15;
    const int n0 = lo + blockIdx.x * 64 + w * 16;
    if (n0 >= hi) return;

    const half8* wvs3 = (const half8*)(wsp + F_WVS3);
    const half8* wx2  = (const half8*)(wsp + F_WX2);

#pragma unroll 1
    for (int x = 0; x < 3; ++x) {
        half8 av;
        {
            int nn = n0 + l16; if (nn >= NN) nn = NN - 1;
#pragma unroll
            for (int j = 0; j < 8; j++)
                av[j] = (_Float16)feat1o[(size_t)nn * 96 + (l4 * 8 + j) * 3 + x];
        }
#pragma unroll 4
        for (int nfb = 0; nfb < 128; ++nfb) {
            f32x4 acc = __builtin_amdgcn_mfma_f32_16x16x32_f16(
                av, wvs3[nfb * 64 + lane], (f32x4){0.f,0.f,0.f,0.f}, 0, 0, 0);
#pragma unroll
            for (int reg = 0; reg < 4; reg++) {
                int n = n0 + l4 * 4 + reg;
                if (n < hi && n < NN)
                    GH[(size_t)(n - lo) * 10240 + 4096 + x * 2048 + nfb * 16 + l16] =
                        (_Float16)acc[reg];
            }
        }
#pragma unroll
        for (int nfc = 0; nfc < 2; ++nfc) {
            f32x4 acc = __builtin_amdgcn_mfma_f32_16x16x32_f16(
                av, wx2[nfc * 64 + lane], (f32x4){0.f,0.f,0.f,0.f}, 0, 0, 0);
#pragma unroll
            for (int reg = 0; reg < 4; reg++) {
                int n = n0 + l4 * 4 + reg;
                if (n < hi && n < NN)
                    aux[(size_t)n * 128 + 32 + x * 32 + nfc * 16 + l16] =
                        (_Float16)acc[reg];
            }
        }
    }
}

// ---------------------------------------------------------------------------
// FUSED node-wave kernel: MLP once, msg0 + msg1 per 16-edge tile.
__global__ __launch_bounds__(256, 2) void msg01_node_kernel(
    const float* __restrict__ feat1o,
    const float* __restrict__ edge_attr,
    const float* __restrict__ pos,
    const float* __restrict__ b1, const float* __restrict__ b2,
    const float* __restrict__ b3,
    const char* __restrict__ wsp,
    const _Float16* __restrict__ GH,
    int lo, int hi,
    _Float16* __restrict__ msg0, _Float16* __restrict__ msg1)
{
    __shared__ half8 wml[1536];
    __shared__ __align__(16) unsigned short xch[4][16 * 104];
    __shared__ float relb[4][16][4];
    __shared__ unsigned short auxl[4][128];

    const int tid = threadIdx.x, w = tid >> 6, lane = tid & 63;
    const int l4 = lane >> 4, l16 = lane & 15;

    {
        const half8* wm = (const half8*)(wsp + F_WMLP);
        for (int f = tid; f < 1536; f += 256) wml[f] = wm[f];
    }
    __syncthreads();

    const int n = lo + blockIdx.x * 4 + w;
    if (n >= hi) return;
    const int deg = ((const int*)(wsp + F_OUTD))[n];
    if (deg == 0) return;
    const int base = ((const int*)(wsp + F_PSP))[n];
    const int* dstP = (const int*)(wsp + F_DSTP);
    const int* peP  = (const int*)(wsp + F_PEP);
    const int* pdP  = (const int*)(wsp + F_PDP);

    const float pn0 = pos[n * 3 + 0], pn1 = pos[n * 3 + 1], pn2 = pos[n * 3 + 2];

    // per-node registers: G (8 frags), H (12 frags), wvv (4), v (24 f32)
    const size_t kbase = (size_t)(n - lo) * 10240;
    half8 Gr[8];
    {
        const half8* gn = (const half8*)(GH + kbase);
#pragma unroll
        for (int f = 0; f < 8; f++) Gr[f] = gn[f * 64 + lane];
    }
    half8 Hf[2][6];
    {
        const _Float16* Hg = GH + kbase + 4096;
#pragma unroll
        for (int kf = 0; kf < 2; kf++)
#pragma unroll
            for (int nf = 0; nf < 6; nf++) {
                int x = nf >> 1, c0 = (nf & 1) * 16;
#pragma unroll
                for (int j = 0; j < 8; j++) {
                    int h = kf * 32 + l4 * 8 + j;
                    Hf[kf][nf][j] = Hg[x * 2048 + h * 32 + c0 + l16];
                }
            }
    }
    half8 wvvf[4];
    {
        const half8* wvvp = (const half8*)(wsp + F_WVV);
#pragma unroll
        for (int nf = 0; nf < 4; nf++) wvvf[nf] = wvvp[nf * 64 + lane];
    }
    float vx[8], vy[8], vz[8];
#pragma unroll
    for (int j = 0; j < 8; j++) {
        int d = l4 * 8 + j;
        vx[j] = feat1o[(size_t)n * 96 + d * 3 + 0];
        vy[j] = feat1o[(size_t)n * 96 + d * 3 + 1];
        vz[j] = feat1o[(size_t)n * 96 + d * 3 + 2];
    }
    float bias[3][4];
#pragma unroll
    for (int nf = 0; nf < 4; nf++) {
        bias[0][nf] = b1[nf * 16 + l16];
        bias[1][nf] = b2[nf * 16 + l16];
        bias[2][nf] = b3[nf * 16 + l16];
    }
    {
        const _Float16* ag = (const _Float16*)(wsp + F_AUX) + (size_t)n * 128;
        for (int i = lane; i < 128; i += 64) auxl[w][i] = h2u(ag[i]);
    }

    unsigned short* x = xch[w];
    const int ntile = (deg + 15) >> 4;
    const int sw16 = (l16 & 7) << 3;

    for (int t = 0; t < ntile; ++t) {
        const int r0 = t * 16;
        int rowc = r0 + l16; if (rowc > deg - 1) rowc = deg - 1;
        const int pe = peP[base + rowc];
        const int dd = dstP[base + rowc];
        const float rel0 = pos[dd * 3 + 0] - pn0;
        const float rel1 = pos[dd * 3 + 1] - pn1;
        const float rel2 = pos[dd * 3 + 2] - pn2;
        if (l4 == 0) {
            relb[w][l16][0] = rel0; relb[w][l16][1] = rel1; relb[w][l16][2] = rel2;
        }

        // ---- MLP (once) ----
        half8 af[2];
        {
            const float* ap = edge_attr + (size_t)pe * 64 + l4 * 8;
            af[0] = pack8(*(const float4*)ap, *(const float4*)(ap + 4));
            af[1] = pack8(*(const float4*)(ap + 32), *(const float4*)(ap + 36));
        }
#pragma unroll
        for (int layer = 0; layer < 3; ++layer) {
            f32x4 acc[4];
#pragma unroll
            for (int nf = 0; nf < 4; nf++) acc[nf] = (f32x4){0.f,0.f,0.f,0.f};
#pragma unroll
            for (int kf = 0; kf < 2; kf++)
#pragma unroll
                for (int nf = 0; nf < 4; nf++)
                    acc[nf] = __builtin_amdgcn_mfma_f32_16x16x32_f16(
                        af[kf], wml[(layer * 8 + kf * 4 + nf) * 64 + lane],
                        acc[nf], 0, 0, 0);
#pragma unroll
            for (int nf = 0; nf < 4; nf++)
#pragma unroll
                for (int reg = 0; reg < 4; reg++) {
                    int row = l4 * 4 + reg;
                    int col = nf * 16 + l16;
                    float v = acc[nf][reg] + bias[layer][nf];
                    if (layer < 2) v = silu_f(v);
                    x[row * 104 + (col ^ ((row & 7) << 3))] = h2u((_Float16)v);
                }
            if (layer < 2) {
#pragma unroll
                for (int kf = 0; kf < 2; kf++)
                    af[kf] = *(const half8*)&x[l16 * 104 + ((kf * 32 + l4 * 8) ^ sw16)];
            }
        }
        half8 esf[2];
#pragma unroll
        for (int kf = 0; kf < 2; kf++)
            esf[kf] = *(const half8*)&x[l16 * 104 + ((kf * 32 + l4 * 8) ^ sw16)];

        // ---- msg0: es@G + dotv@wvv ----
        {
            f32x4 acc[4];
#pragma unroll
            for (int nf = 0; nf < 4; nf++) acc[nf] = (f32x4){0.f,0.f,0.f,0.f};
#pragma unroll
            for (int kf = 0; kf < 2; kf++)
#pragma unroll
                for (int nf = 0; nf < 4; nf++)
                    acc[nf] = __builtin_amdgcn_mfma_f32_16x16x32_f16(
                        esf[kf], Gr[kf * 4 + nf], acc[nf], 0, 0, 0);
            half8 dvf;
#pragma unroll
            for (int j = 0; j < 8; j++)
                dvf[j] = (_Float16)(vx[j] * rel0 + vy[j] * rel1 + vz[j] * rel2);
#pragma unroll
            for (int nf = 0; nf < 4; nf++)
                acc[nf] = __builtin_amdgcn_mfma_f32_16x16x32_f16(
                    dvf, wvvf[nf], acc[nf], 0, 0, 0);
#pragma unroll
            for (int nf = 0; nf < 4; nf++)
#pragma unroll
                for (int reg = 0; reg < 4; reg++) {
                    int row = l4 * 4 + reg;
                    int col = nf * 16 + l16;
                    x[row * 104 + (col ^ ((row & 7) << 3))] = h2u((_Float16)acc[nf][reg]);
                }
#pragma unroll
            for (int i = 0; i < 2; i++) {
                int row16 = i * 8 + (lane >> 3);
                if (r0 + row16 < deg) {
                    int rowD = pdP[base + r0 + row16];
                    int c8 = lane & 7;
                    half8 v = *(const half8*)&x[row16 * 104 + ((c8 * 8) ^ ((row16 & 7) << 3))];
                    *(half8*)(msg0 + (size_t)rowD * 64 + c8 * 8) = v;
                }
            }
        }

        // ---- msg1: es@H + sv/cross epilogue ----
        {
            f32x4 acc1[6];
#pragma unroll
            for (int nf = 0; nf < 6; nf++) acc1[nf] = (f32x4){0.f,0.f,0.f,0.f};
#pragma unroll
            for (int kf = 0; kf < 2; kf++)
#pragma unroll
                for (int nf = 0; nf < 6; nf++)
                    acc1[nf] = __builtin_amdgcn_mfma_f32_16x16x32_f16(
                        esf[kf], Hf[kf][nf], acc1[nf], 0, 0, 0);
#pragma unroll
            for (int nf = 0; nf < 6; nf++) {
                const int xx = nf >> 1;
                const int x1 = (xx + 1) % 3, x2 = (xx + 2) % 3;
                const int c = (nf & 1) * 16 + l16;
                const float gv  = (float)u2h(auxl[w][c]);
                const float cw1 = (float)u2h(auxl[w][32 + x1 * 32 + c]);
                const float cw2 = (float)u2h(auxl[w][32 + x2 * 32 + c]);
#pragma unroll
                for (int reg = 0; reg < 4; reg++) {
                    int row = l4 * 4 + reg;
                    float rx  = relb[w][row][xx];
                    float rx1 = relb[w][row][x1];
                    float rx2 = relb[w][row][x2];
                    float val = acc1[nf][reg] + gv * rx + rx2 * cw1 - rx1 * cw2;
                    int col = nf * 16 + l16;
                    x[row * 104 + (col ^ ((row & 3) << 3))] = h2u((_Float16)val);
                }
            }
            const int rowS = lane >> 2;
            if (r0 + rowS < deg) {
                int rowD = pdP[base + r0 + rowS];
                const int swr = (rowS & 3) << 3;
#pragma unroll
                for (int t3 = 0; t3 < 3; t3++) {
                    int co = ((lane & 3) + 4 * t3) * 8;
                    half8 v = *(const half8*)&x[rowS * 104 + (co ^ swr)];
                    *(half8*)(msg1 + (size_t)rowD * 96 + co) = v;
                }
            }
        }
    }
}

// ---------------------------------------------------------------------------
// gathers (contiguous dst ranges) — shared by both paths.
__global__ __launch_bounds__(256) void gather0_kernel(
    const float* __restrict__ feat0e,
    const float* __restrict__ Wg, const float* __restrict__ bg,
    const char* __restrict__ wsp, const _Float16* __restrict__ msg0,
    float* __restrict__ out)
{
    __shared__ float Wgl[2048];
    __shared__ float ag[4][64];
    const int tid = threadIdx.x, w = tid >> 6, lane = tid & 63;
    for (int t = tid; t < 2048; t += 256) Wgl[t] = Wg[t];

    const int n = blockIdx.x * 4 + w;
    const int* rs = (const int*)(wsp + OFF_RS);
    const int i0 = rs[n], i1 = rs[n + 1];
    const int r8 = lane >> 3, c8 = lane & 7;

    float a[8];
#pragma unroll
    for (int j = 0; j < 8; j++) a[j] = 0.f;
    for (int i = i0 + r8; i < i1; i += 8) {
        half8 m = *(const half8*)(msg0 + (size_t)i * 64 + c8 * 8);
#pragma unroll
        for (int j = 0; j < 8; j++) a[j] += (float)m[j];
    }
#pragma unroll
    for (int s = 8; s < 64; s <<= 1)
#pragma unroll
        for (int j = 0; j < 8; j++) a[j] += __shfl_xor(a[j], s);
    if (r8 == 0)
#pragma unroll
        for (int j = 0; j < 8; j++) ag[w][c8 * 8 + j] = a[j];
    __syncthreads();

    const float inv = 1.0f / fmaxf((float)(i1 - i0), 1.0f);
    float av = ag[w][lane] * inv;
    out[(size_t)n * 160 + lane] = silu_f(av) + feat0e[(size_t)n * 64 + lane];

    if (lane < 32) {
        float gs = bg[lane];
#pragma unroll
        for (int p = 0; p < 64; ++p) gs = fmaf(ag[w][p] * inv, Wgl[p * 32 + lane], gs);
        out[(size_t)n * 160 + 64 + lane] = silu_f(gs);
    }
}

__global__ __launch_bounds__(256) void gather1_kernel(
    const float* __restrict__ feat1o,
    const char* __restrict__ wsp, const _Float16* __restrict__ msg1,
    float* __restrict__ out)
{
    __shared__ float ag1[4][96];
    __shared__ float gl[4][32];
    const int tid = threadIdx.x, w = tid >> 6, lane = tid & 63;
    const int n = blockIdx.x * 4 + w;
    const int* rs = (const int*)(wsp + OFF_RS);
    const int i0 = rs[n], i1 = rs[n + 1];

    if (lane < 32) gl[w][lane] = out[(size_t)n * 160 + 64 + lane];

    const int r4 = lane >> 4, c12 = lane & 15;
    float a[8];
#pragma unroll
    for (int j = 0; j < 8; j++) a[j] = 0.f;
    if (c12 < 12)
        for (int i = i0 + r4; i < i1; i += 4) {
            half8 m = *(const half8*)(msg1 + (size_t)i * 96 + c12 * 8);
#pragma unroll
            for (int j = 0; j < 8; j++) a[j] += (float)m[j];
        }
#pragma unroll
    for (int s = 16; s < 64; s <<= 1)
#pragma unroll
        for (int j = 0; j < 8; j++) a[j] += __shfl_xor(a[j], s);
    if (r4 == 0 && c12 < 12)
#pragma unroll
        for (int j = 0; j < 8; j++) ag1[w][c12 * 8 + j] = a[j];
    __syncthreads();

    const float inv = 1.0f / fmaxf((float)(i1 - i0), 1.0f);
#pragma unroll
    for (int t = 0; t < 2; t++) {
        int idx = t * 64 + lane;
        if (idx < 96) {
            int c = idx / 3, xx = idx - 3 * c;
            float v = ag1[w][xx * 32 + c] * inv * gl[w][c] + feat1o[(size_t)n * 96 + idx];
            out[(size_t)n * 160 + 64 + idx] = v;
        }
    }
}

// ===========================================================================
// ===== FALLBACK (verified r6 big-tier) =====================================
__global__ __launch_bounds__(256) void prep_kernel(
    const float* __restrict__ wss, const float* __restrict__ wvv,
    const float* __restrict__ wsv, const float* __restrict__ wvs,
    const float* __restrict__ wx,
    const float* __restrict__ W1, const float* __restrict__ W2,
    const float* __restrict__ W3, char* __restrict__ ws, int maxid)
{
    int id = blockIdx.x * 256 + threadIdx.x;
    if (id >= maxid) return;
    int l = id & 63;
    int l4 = l >> 4, l16 = l & 15;
    half8 o;
    _Float16* dst;
    if (id < 32768) {
        int p = id >> 9; int frag = (id >> 6) & 7;
        int kf = frag >> 2, nf = frag & 3;
#pragma unroll
        for (int j = 0; j < 8; j++) {
            int h = kf * 32 + l4 * 8 + j, oo = nf * 16 + l16;
            o[j] = (_Float16)wss[((size_t)p * 64 + h) * 64 + oo];
        }
        dst = (_Float16*)(ws + OFF_WSS) + (size_t)id * 8;
    } else if (id < 40960) {
        int i = id - 32768;
        int f = i >> 6;
        int chunk = f >> 3, kf = (f >> 2) & 1, nfl = f & 3;
#pragma unroll
        for (int j = 0; j < 8; j++) {
            int h = kf * 32 + l4 * 8 + j;
            int col = chunk * 64 + nfl * 16 + l16;
            int d = col >> 5, c = col & 31;
            o[j] = (_Float16)wvs[((size_t)d * 64 + h) * 32 + c];
        }
        dst = (_Float16*)(ws + OFF_WVS2) + (size_t)i * 8;
    } else if (id < 41216) {
        int i = id - 40960; int nf = i >> 6;
#pragma unroll
        for (int j = 0; j < 8; j++)
            o[j] = (_Float16)wvv[(l4 * 8 + j) * 64 + nf * 16 + l16];
        dst = (_Float16*)(ws + OFF_WVV) + (size_t)i * 8;
    } else if (id < 41472) {
        int i = id - 41216; int frag = i >> 6;
        int kf = frag >> 1, nf = frag & 1;
#pragma unroll
        for (int j = 0; j < 8; j++)
            o[j] = (_Float16)wsv[(kf * 32 + l4 * 8 + j) * 32 + nf * 16 + l16];
        dst = (_Float16*)(ws + OFF_WSV) + (size_t)i * 8;
    } else if (id < 41600) {
        int i = id - 41472; int nf = i >> 6;
#pragma unroll
        for (int j = 0; j < 8; j++)
            o[j] = (_Float16)wx[(l4 * 8 + j) * 32 + nf * 16 + l16];
        dst = (_Float16*)(ws + OFF_WX) + (size_t)i * 8;
    } else if (id < 43136) {
        int i = id - 41600; int f = i >> 6;
        int layer = f >> 3, kf = (f >> 2) & 1, nf = f & 3;
        const float* W = layer == 0 ? W1 : (layer == 1 ? W2 : W3);
#pragma unroll
        for (int j = 0; j < 8; j++)
            o[j] = (_Float16)W[(kf * 32 + l4 * 8 + j) * 64 + nf * 16 + l16];
        dst = (_Float16*)(ws + OFF_WMLP) + (size_t)i * 8;
    } else {
        int i = id - 43136;
        int f = i >> 6;
        int q = f >> 3, kfp = (f >> 2) & 1, nfp = f & 3;
#pragma unroll
        for (int j = 0; j < 8; j++) {
            int p = kfp * 32 + l4 * 8 + j;
            int cc = q * 64 + nfp * 16 + l16;
            int jc = cc & 7, lc = (cc >> 3) & 63, fi = cc >> 9;
            int kfc = fi >> 2, nfc = fi & 3;
            int h = kfc * 32 + (lc >> 4) * 8 + jc;
            int oo = nfc * 16 + (lc & 15);
            o[j] = (_Float16)wss[((size_t)p * 64 + h) * 64 + oo];
        }
        dst = (_Float16*)(ws + OFF_WSSG) + (size_t)i * 8;
    }
    *(half8*)dst = o;
}

__global__ __launch_bounds__(256, 2) void gG_kernel(
    const float* __restrict__ feat0e, const char* __restrict__ wsp,
    int lo, int hi, _Float16* __restrict__ G)
{
    const int tid = threadIdx.x, w = tid >> 6, lane = tid & 63;
    const int l4 = lane >> 4, l16 = lane & 15;
    const int n0 = lo + blockIdx.x * 64 + w * 16;
    if (n0 >= hi) return;

    half8 af[2];
    {
        int n = n0 + l16; if (n >= NN) n = NN - 1;
        const float* sp = feat0e + (size_t)n * 64 + l4 * 8;
        af[0] = pack8(*(const float4*)sp, *(const float4*)(sp + 4));
        af[1] = pack8(*(const float4*)(sp + 32), *(const float4*)(sp + 36));
    }
    const half8* wg = (const half8*)(wsp + OFF_WSSG);
    for (int q = 0; q < 64; ++q) {
        f32x4 acc[4];
#pragma unroll
        for (int nf = 0; nf < 4; nf++) acc[nf] = (f32x4){0.f,0.f,0.f,0.f};
#pragma unroll
        for (int kf = 0; kf < 2; kf++)
#pragma unroll
            for (int nf = 0; nf < 4; nf++)
                acc[nf] = __builtin_amdgcn_mfma_f32_16x16x32_f16(
                    af[kf], wg[(q * 8 + kf * 4 + nf) * 64 + lane], acc[nf], 0, 0, 0);
#pragma unroll
        for (int nf = 0; nf < 4; nf++)
#pragma unroll
            for (int reg = 0; reg < 4; reg++) {
                int n = n0 + l4 * 4 + reg;
                if (n < hi && n < NN)
                    G[(size_t)(n - lo) * 4096 + q * 64 + nf * 16 + l16] =
                        (_Float16)acc[nf][reg];
            }
    }
}

__device__ __forceinline__ void mlp_wave(
    const float* __restrict__ edge_attr,
    const float* __restrict__ b1, const float* __restrict__ b2,
    const float* __restrict__ b3,
    const char* __restrict__ wsp,
    const int* __restrict__ pel_w,
    unsigned short* __restrict__ xch,
    int lane, half8 esf[4][2])
{
    const int l4 = lane >> 4, l16 = lane & 15;
    const half8* wm = (const half8*)(wsp + OFF_WMLP);

    float bias[3][4];
#pragma unroll
    for (int nf = 0; nf < 4; nf++) {
        bias[0][nf] = b1[nf * 16 + l16];
        bias[1][nf] = b2[nf * 16 + l16];
        bias[2][nf] = b3[nf * 16 + l16];
    }

    half8 af[4][2];
#pragma unroll
    for (int mf = 0; mf < 4; mf++) {
        int e = pel_w[mf * 16 + l16];
        const float* p = edge_attr + (size_t)e * 64 + l4 * 8;
#pragma unroll
        for (int kf = 0; kf < 2; kf++)
            af[mf][kf] = pack8(*(const float4*)(p + kf * 32),
                               *(const float4*)(p + kf * 32 + 4));
    }

#pragma unroll
    for (int layer = 0; layer < 3; ++layer) {
        f32x4 acc[4][4];
#pragma unroll
        for (int mf = 0; mf < 4; mf++)
#pragma unroll
            for (int nf = 0; nf < 4; nf++) acc[mf][nf] = (f32x4){0.f,0.f,0.f,0.f};
#pragma unroll
        for (int kf = 0; kf < 2; kf++)
#pragma unroll
            for (int mf = 0; mf < 4; mf++)
#pragma unroll
                for (int nf = 0; nf < 4; nf++)
                    acc[mf][nf] = __builtin_amdgcn_mfma_f32_16x16x32_f16(
                        af[mf][kf], wm[(layer * 8 + kf * 4 + nf) * 64 + lane],
                        acc[mf][nf], 0, 0, 0);
#pragma unroll
        for (int mf = 0; mf < 4; mf++)
#pragma unroll
            for (int nf = 0; nf < 4; nf++)
#pragma unroll
                for (int reg = 0; reg < 4; reg++) {
                    int row = mf * 16 + l4 * 4 + reg;
                    int col = nf * 16 + l16;
                    float v = acc[mf][nf][reg] + bias[layer][nf];
                    if (layer < 2) v = silu_f(v);
                    xch[row * 64 + (col ^ ((row & 7) << 3))] = h2u((_Float16)v);
                }
        if (layer < 2) {
#pragma unroll
            for (int mf = 0; mf < 4; mf++)
#pragma unroll
                for (int kf = 0; kf < 2; kf++) {
                    int row = mf * 16 + l16;
                    int cs = kf * 32 + l4 * 8;
                    af[mf][kf] = *(const half8*)&xch[row * 64 + (cs ^ ((row & 7) << 3))];
                }
        }
    }
#pragma unroll
    for (int mf = 0; mf < 4; mf++)
#pragma unroll
        for (int kf = 0; kf < 2; kf++) {
            int row = mf * 16 + l16;
            int cs = kf * 32 + l4 * 8;
            esf[mf][kf] = *(const half8*)&xch[row * 64 + (cs ^ ((row & 7) << 3))];
        }
}

__global__ __launch_bounds__(256, 3) void msg0e_node_kernel(
    const float* __restrict__ feat1o,
    const float* __restrict__ edge_attr,
    const float* __restrict__ pos,
    const float* __restrict__ b1, const float* __restrict__ b2,
    const float* __restrict__ b3,
    const char* __restrict__ wsp,
    const _Float16* __restrict__ G,
    int lo, int hi,
    _Float16* __restrict__ msg0)
{
    __shared__ half8 wml[1536];
    __shared__ __align__(16) unsigned short xch[4][1024];

    const int tid = threadIdx.x, w = tid >> 6, lane = tid & 63;
    const int l4 = lane >> 4, l16 = lane & 15;

    {
        const half8* wm = (const half8*)(wsp + OFF_WMLP);
        for (int f = tid; f < 1536; f += 256) wml[f] = wm[f];
    }
    __syncthreads();

    const int n = lo + blockIdx.x * 4 + w;
    if (n >= hi) return;
    const int deg = ((const int*)(wsp + OFF_OUTD))[n];
    if (deg == 0) return;
    const int base = ((const int*)(wsp + OFF_PSP))[n];
    const int* dstP = (const int*)(wsp + OFF_DSTP);
    const int* peP  = (const int*)(wsp + OFF_PEP);
    const int* pdP  = (const int*)(wsp + OFF_PDP);

    const float pn0 = pos[n * 3 + 0], pn1 = pos[n * 3 + 1], pn2 = pos[n * 3 + 2];
    half8 Gr[8];
    {
        const half8* gn = (const half8*)G + (size_t)(n - lo) * 512;
#pragma unroll
        for (int f = 0; f < 8; f++) Gr[f] = gn[f * 64 + lane];
    }
    half8 wvvf[4];
    {
        const half8* wvvp = (const half8*)(wsp + OFF_WVV);
#pragma unroll
        for (int nf = 0; nf < 4; nf++) wvvf[nf] = wvvp[nf * 64 + lane];
    }
    float vx[8], vy[8], vz[8];
#pragma unroll
    for (int j = 0; j < 8; j++) {
        int d = l4 * 8 + j;
        vx[j] = feat1o[(size_t)n * 96 + d * 3 + 0];
        vy[j] = feat1o[(size_t)n * 96 + d * 3 + 1];
        vz[j] = feat1o[(size_t)n * 96 + d * 3 + 2];
    }
    float bias[3][4];
#pragma unroll
    for (int nf = 0; nf < 4; nf++) {
        bias[0][nf] = b1[nf * 16 + l16];
        bias[1][nf] = b2[nf * 16 + l16];
        bias[2][nf] = b3[nf * 16 + l16];
    }

    unsigned short* x = xch[w];
    const int ntile = (deg + 15) >> 4;
    const int sw16 = (l16 & 7) << 3;

    for (int t = 0; t < ntile; ++t) {
        const int r0 = t * 16;
        int rowc = r0 + l16; if (rowc > deg - 1) rowc = deg - 1;
        const int pe = peP[base + rowc];
        const int dd = dstP[base + rowc];
        const float rel0 = pos[dd * 3 + 0] - pn0;
        const float rel1 = pos[dd * 3 + 1] - pn1;
        const float rel2 = pos[dd * 3 + 2] - pn2;

        half8 af[2];
        {
            const float* ap = edge_attr + (size_t)pe * 64 + l4 * 8;
            af[0] = pack8(*(const float4*)ap, *(const float4*)(ap + 4));
            af[1] = pack8(*(const float4*)(ap + 32), *(const float4*)(ap + 36));
        }
#pragma unroll
        for (int layer = 0; layer < 3; ++layer) {
            f32x4 acc[4];
#pragma unroll
            for (int nf = 0; nf < 4; nf++) acc[nf] = (f32x4){0.f,0.f,0.f,0.f};
#pragma unroll
            for (int kf = 0; kf < 2; kf++)
#pragma unroll
                for (int nf = 0; nf < 4; nf++)
                    acc[nf] = __builtin_amdgcn_mfma_f32_16x16x32_f16(
                        af[kf], wml[(layer * 8 + kf * 4 + nf) * 64 + lane],
                        acc[nf], 0, 0, 0);
#pragma unroll
            for (int nf = 0; nf < 4; nf++)
#pragma unroll
                for (int reg = 0; reg < 4; reg++) {
                    int row = l4 * 4 + reg;
                    int col = nf * 16 + l16;
                    float v = acc[nf][reg] + bias[layer][nf];
                    if (layer < 2) v = silu_f(v);
                    x[row * 64 + (col ^ ((row & 7) << 3))] = h2u((_Float16)v);
                }
            if (layer < 2) {
#pragma unroll
                for (int kf = 0; kf < 2; kf++)
                    af[kf] = *(const half8*)&x[l16 * 64 + ((kf * 32 + l4 * 8) ^ sw16)];
            }
        }
        half8 esf[2];
#pragma unroll
        for (int kf = 0; kf < 2; kf++)
            esf[kf] = *(const half8*)&x[l16 * 64 + ((kf * 32 + l4 * 8) ^ sw16)];

        f32x4 acc[4];
#pragma unroll
        for (int nf = 0; nf < 4; nf++) acc[nf] = (f32x4){0.f,0.f,0.f,0.f};
#pragma unroll
        for (int kf = 0; kf < 2; kf++)
#pragma unroll
            for (int nf = 0; nf < 4; nf++)
                acc[nf] = __builtin_amdgcn_mfma_f32_16x16x32_f16(
                    esf[kf], Gr[kf * 4 + nf], acc[nf], 0, 0, 0);
        half8 dvf;
#pragma unroll
        for (int j = 0; j < 8; j++)
            dvf[j] = (_Float16)(vx[j] * rel0 + vy[j] * rel1 + vz[j] * rel2);
#pragma unroll
        for (int nf = 0; nf < 4; nf++)
            acc[nf] = __builtin_amdgcn_mfma_f32_16x16x32_f16(
                dvf, wvvf[nf], acc[nf], 0, 0, 0);

#pragma unroll
        for (int nf = 0; nf < 4; nf++)
#pragma unroll
            for (int reg = 0; reg < 4; reg++) {
                int row = l4 * 4 + reg;
                int col = nf * 16 + l16;
                x[row * 64 + (col ^ ((row & 7) << 3))] = h2u((_Float16)acc[nf][reg]);
            }
#pragma unroll
        for (int i = 0; i < 2; i++) {
            int row16 = i * 8 + (lane >> 3);
            if (r0 + row16 < deg) {
                int rowD = pdP[base + r0 + row16];
                int c8 = lane & 7;
                half8 v = *(const half8*)&x[row16 * 64 + ((c8 * 8) ^ ((row16 & 7) << 3))];
                *(half8*)(msg0 + (size_t)rowD * 64 + c8 * 8) = v;
            }
        }
    }
}

__global__ __launch_bounds__(256, 2) void msg1o_kernel(
    const float* __restrict__ feat0e,
    const float* __restrict__ feat1o,
    const float* __restrict__ edge_attr,
    const float* __restrict__ pos,
    const float* __restrict__ b1, const float* __restrict__ b2,
    const float* __restrict__ b3,
    const char* __restrict__ wsp,
    _Float16* __restrict__ msg1)
{
    __shared__ unsigned short vt[4][6144];
    __shared__ float rell[4][64][3];
    __shared__ int srcl[4][64];
    __shared__ int pel[4][64];

    const int tid = threadIdx.x, w = tid >> 6, lane = tid & 63;
    const int l4 = lane >> 4, l16 = lane & 15;
    const long i0 = (long)blockIdx.x * 256 + w * 64;

    {
        long p = i0 + lane;
        int s_ = ((const int*)(wsp + OFF_SRCA))[p];
        int d_ = ((const int*)(wsp + OFF_DSTA))[p];
        pel[w][lane] = ((const int*)(wsp + OFF_PE))[p];
        srcl[w][lane] = s_;
        rell[w][lane][0] = pos[d_ * 3 + 0] - pos[s_ * 3 + 0];
        rell[w][lane][1] = pos[d_ * 3 + 1] - pos[s_ * 3 + 1];
        rell[w][lane][2] = pos[d_ * 3 + 2] - pos[s_ * 3 + 2];
    }
    __syncthreads();

    half8 esf[4][2];
    mlp_wave(edge_attr, b1, b2, b3, wsp, pel[w], vt[w], lane, esf);
    __syncthreads();

    {
        const float* vp = feat1o + (size_t)srcl[w][lane] * 96;
#pragma unroll
        for (int q = 0; q < 24; q++) {
            float4 f = *(const float4*)(vp + q * 4);
            vt[w][(q * 4 + 0) * 64 + lane] = h2u((_Float16)f.x);
            vt[w][(q * 4 + 1) * 64 + lane] = h2u((_Float16)f.y);
            vt[w][(q * 4 + 2) * 64 + lane] = h2u((_Float16)f.z);
            vt[w][(q * 4 + 3) * 64 + lane] = h2u((_Float16)f.w);
        }
    }
    __syncthreads();

    const half8* wvs2p = (const half8*)(wsp + OFF_WVS2);
    const half8* wsvp  = (const half8*)(wsp + OFF_WSV);
    const half8* wxp   = (const half8*)(wsp + OFF_WX);

    f32x4 acc1[4][3][2];
#pragma unroll
    for (int g = 0; g < 4; g++)
#pragma unroll
        for (int x = 0; x < 3; x++)
#pragma unroll
            for (int ch = 0; ch < 2; ch++) acc1[g][x][ch] = (f32x4){0.f,0.f,0.f,0.f};

#pragma unroll 2
    for (int ck = 0; ck < 16; ++ck) {
        half8 bf[2][4];
#pragma unroll
        for (int kf = 0; kf < 2; kf++)
#pragma unroll
            for (int nfl = 0; nfl < 4; nfl++)
                bf[kf][nfl] = wvs2p[(ck * 8 + kf * 4 + nfl) * 64 + lane];
#pragma unroll
        for (int g = 0; g < 4; g++) {
            f32x4 tacc[4];
#pragma unroll
            for (int nfl = 0; nfl < 4; nfl++) tacc[nfl] = (f32x4){0.f,0.f,0.f,0.f};
#pragma unroll
            for (int kf = 0; kf < 2; kf++)
#pragma unroll
                for (int nfl = 0; nfl < 4; nfl++)
                    tacc[nfl] = __builtin_amdgcn_mfma_f32_16x16x32_f16(
                        esf[g][kf], bf[kf][nfl], tacc[nfl], 0, 0, 0);
#pragma unroll
            for (int dl = 0; dl < 2; dl++) {
                int d = ck * 2 + dl;
#pragma unroll
                for (int x = 0; x < 3; x++) {
                    half4 hv = *(const half4*)&vt[w][(d * 3 + x) * 64 + g * 16 + l4 * 4];
                    f32x4 vf = __builtin_convertvector(hv, f32x4);
                    acc1[g][x][0] += vf * tacc[dl * 2 + 0];
                    acc1[g][x][1] += vf * tacc[dl * 2 + 1];
                }
            }
        }
    }

    {
        half8 bsv[2][2];
#pragma unroll
        for (int kf = 0; kf < 2; kf++)
#pragma unroll
            for (int nf = 0; nf < 2; nf++)
                bsv[kf][nf] = wsvp[(size_t)(kf * 2 + nf) * 64 + lane];
#pragma unroll
        for (int g = 0; g < 4; g++) {
            int erow = g * 16 + l16;
            const float* sp = feat0e + (size_t)srcl[w][erow] * 64 + l4 * 8;
            half8 sf[2];
#pragma unroll
            for (int kf = 0; kf < 2; kf++)
                sf[kf] = pack8(*(const float4*)(sp + kf * 32),
                               *(const float4*)(sp + kf * 32 + 4));
#pragma unroll
            for (int x = 0; x < 3; x++) {
                _Float16 rl = (_Float16)rell[w][erow][x];
#pragma unroll
                for (int kf = 0; kf < 2; kf++) {
                    half8 a = sf[kf] * rl;
#pragma unroll
                    for (int nf = 0; nf < 2; nf++)
                        acc1[g][x][nf] = __builtin_amdgcn_mfma_f32_16x16x32_f16(
                            a, bsv[kf][nf], acc1[g][x][nf], 0, 0, 0);
                }
            }
        }
    }

    {
        half8 bx[2];
        bx[0] = wxp[lane];
        bx[1] = wxp[64 + lane];
#pragma unroll
        for (int g = 0; g < 4; g++) {
            f32x4 cx[3][2];
#pragma unroll
            for (int xp = 0; xp < 3; xp++) {
                half8 av;
#pragma unroll
                for (int j = 0; j < 8; j++)
                    av[j] = u2h(vt[w][((l4 * 8 + j) * 3 + xp) * 64 + g * 16 + l16]);
#pragma unroll
                for (int nf = 0; nf < 2; nf++)
                    cx[xp][nf] = __builtin_amdgcn_mfma_f32_16x16x32_f16(
                        av, bx[nf], (f32x4){0.f,0.f,0.f,0.f}, 0, 0, 0);
            }
            f32x4 r[3];
#pragma unroll
            for (int x = 0; x < 3; x++)
#pragma unroll
                for (int reg = 0; reg < 4; reg++)
                    r[x][reg] = rell[w][g * 16 + l4 * 4 + reg][x];
#pragma unroll
            for (int x = 0; x < 3; x++) {
                const int x1 = (x + 1) % 3, x2 = (x + 2) % 3;
#pragma unroll
                for (int ch = 0; ch < 2; ch++)
                    acc1[g][x][ch] += r[x2] * cx[x1][ch] - r[x1] * cx[x2][ch];
            }
        }
    }

    __syncthreads();
#pragma unroll
    for (int g = 0; g < 4; g++)
#pragma unroll
        for (int reg = 0; reg < 4; reg++) {
            int row = g * 16 + l4 * 4 + reg;
            int sw = (row & 3) << 3;
#pragma unroll
            for (int x = 0; x < 3; x++)
#pragma unroll
                for (int ch = 0; ch < 2; ch++) {
                    int c32 = ch * 16 + l16;
                    vt[w][row * 96 + x * 32 + (c32 ^ sw)] = h2u((_Float16)acc1[g][x][ch][reg]);
                }
        }
#pragma unroll
    for (int tt = 0; tt < 12; tt++) {
        int x = tt >> 2, rem = (tt & 3) * 8;
        int col = x * 32 + (rem ^ ((lane & 3) << 3));
        half8 v = *(const half8*)&vt[w][lane * 96 + col];
        *(half8*)(msg1 + (size_t)(i0 + lane) * 96 + tt * 8) = v;
    }
}

// ---------------------------------------------------------------------------
extern "C" void kernel_launch(void* const* d_in, const int* in_sizes, int n_in,
                              void* d_out, int out_size, void* d_ws, size_t ws_size,
                              hipStream_t stream) {
    const float* feat0e    = (const float*)d_in[0];
    const float* feat1o    = (const float*)d_in[1];
    const float* edge_attr = (const float*)d_in[2];
    const float* pos       = (const float*)d_in[3];
    const int*   eidx      = (const int*)d_in[4];
    const float* W1 = (const float*)d_in[5];
    const float* b1 = (const float*)d_in[6];
    const float* W2 = (const float*)d_in[7];
    const float* b2 = (const float*)d_in[8];
    const float* W3 = (const float*)d_in[9];
    const float* b3 = (const float*)d_in[10];
    const float* wss    = (const float*)d_in[11];
    const float* wvv    = (const float*)d_in[12];
    const float* wsv    = (const float*)d_in[13];
    const float* wvs    = (const float*)d_in[14];
    const float* wcross = (const float*)d_in[15];
    const float* Wg = (const float*)d_in[16];
    const float* bg = (const float*)d_in[17];

    float* out = (float*)d_out;
    char*  ws  = (char*)d_ws;
    int* hist = (int*)(ws + OFF_HIST);
    int* rs   = (int*)(ws + OFF_RS);
    int* cur  = (int*)(ws + OFF_CUR);
    int* flag = (int*)(ws + OFF_FLAG);

    detect_idx_kernel<<<1, 1, 0, stream>>>(eidx, flag);
    hipMemsetAsync(ws + OFF_HIST, 0, NN * sizeof(int), stream);

    // fused tier selection
    int nppF = 0;
    const int cands[6] = {20000, 10000, 5000, 2500, 1250, 625};
    for (int i = 0; i < 6; ++i)
        if (ws_size >= NEED_F(cands[i])) { nppF = cands[i]; break; }

    if (nppF > 0) {
        int* outd = (int*)(ws + F_OUTD);
        int* psP  = (int*)(ws + F_PSP);
        int* curS = (int*)(ws + F_CURS);
        int* dstP = (int*)(ws + F_DSTP);
        int* peP  = (int*)(ws + F_PEP);
        int* pdP  = (int*)(ws + F_PDP);
        _Float16* aux   = (_Float16*)(ws + F_AUX);
        _Float16* msg0F = (_Float16*)(ws + F_MSG0);
        _Float16* msg1F = (_Float16*)(ws + F_MSG1);
        _Float16* GH    = (_Float16*)(ws + F_GH);

        hipMemsetAsync(ws + F_OUTD, 0, NN * sizeof(int), stream);

        hist2_kernel<<<EE / 256, 256, 0, stream>>>(eidx, flag, hist, outd);
        scan_kernel<<<1, 1024, 0, stream>>>(hist, rs, cur);
        scanP_kernel<<<1, 1024, 0, stream>>>(outd, psP, curS);
        scat_src_kernel<<<EE / 256, 256, 0, stream>>>(
            eidx, flag, curS, cur, dstP, peP, pdP);
        prep2_kernel<<<(43136 + 255) / 256, 256, 0, stream>>>(
            wss, wvv, wsv, wvs, wcross, W1, W2, W3, ws);

        const int S = (NN + nppF - 1) / nppF;
        for (int s = 0; s < S; ++s) {
            int lo = s * nppF;
            int hi = lo + nppF; if (hi > NN) hi = NN;
            gG2_kernel<<<(hi - lo + 63) / 64, 256, 0, stream>>>(
                feat0e, (const char*)ws, lo, hi, GH, aux);
            gH_kernel<<<(hi - lo + 63) / 64, 256, 0, stream>>>(
                feat1o, (const char*)ws, lo, hi, GH, aux);
            msg01_node_kernel<<<(hi - lo + 3) / 4, 256, 0, stream>>>(
                feat1o, edge_attr, pos, b1, b2, b3, (const char*)ws,
                GH, lo, hi, msg0F, msg1F);
        }
        gather0_kernel<<<NN / 4, 256, 0, stream>>>(
            feat0e, Wg, bg, (const char*)ws, msg0F, out);
        gather1_kernel<<<NN / 4, 256, 0, stream>>>(
            feat1o, (const char*)ws, msg1F, out);
    } else {
        // fallback: verified r6 big tier
        int S = 1;
        if (ws_size >= NEED_S(20000)) S = 1;
        else if (ws_size >= NEED_S(10000)) S = 2;
        else if (ws_size >= NEED_S(5000))  S = 4;
        else S = 8;

        int* srca = (int*)(ws + OFF_SRCA);
        int* dsta = (int*)(ws + OFF_DSTA);
        int* pe   = (int*)(ws + OFF_PE);
        int* outd = (int*)(ws + OFF_OUTD);
        int* psP  = (int*)(ws + OFF_PSP);
        int* curS = (int*)(ws + OFF_CURS);
        int* dstP = (int*)(ws + OFF_DSTP);
        int* peP  = (int*)(ws + OFF_PEP);
        int* pdP  = (int*)(ws + OFF_PDP);
        _Float16* msg = (_Float16*)(ws + OFF_MSG);
        _Float16* G   = (_Float16*)(ws + OFF_G);

        hipMemsetAsync(ws + OFF_OUTD, 0, NN * sizeof(int), stream);

        hist2_kernel<<<EE / 256, 256, 0, stream>>>(eidx, flag, hist, outd);
        scan_kernel<<<1, 1024, 0, stream>>>(hist, rs, cur);
        scanP_kernel<<<1, 1024, 0, stream>>>(outd, psP, curS);
        scat_both_kernel<<<EE / 256, 256, 0, stream>>>(
            eidx, flag, curS, cur, dstP, peP, pdP, srca, dsta, pe);
        prep_kernel<<<(75904 + 255) / 256, 256, 0, stream>>>(
            wss, wvv, wsv, wvs, wcross, W1, W2, W3, ws, 75904);

        const int npp = (NN + S - 1) / S;
        for (int s = 0; s < S; ++s) {
            int lo = s * npp;
            int hi = lo + npp; if (hi > NN) hi = NN;
            gG_kernel<<<(hi - lo + 63) / 64, 256, 0, stream>>>(
                feat0e, (const char*)ws, lo, hi, G);
            msg0e_node_kernel<<<(hi - lo + 3) / 4, 256, 0, stream>>>(
                feat1o, edge_attr, pos, b1, b2, b3, (const char*)ws, G, lo, hi, msg);
        }
        gather0_kernel<<<NN / 4, 256, 0, stream>>>(
            feat0e, Wg, bg, (const char*)ws, msg, out);
        msg1o_kernel<<<EE / 256, 256, 0, stream>>>(
            feat0e, feat1o, edge_attr, pos, b1, b2, b3, (const char*)ws, msg);
        gather1_kernel<<<NN / 4, 256, 0, stream>>>(
            feat1o, (const char*)ws, msg, out);
    }
}